// Round 10
// baseline (590.813 us; speedup 1.0000x reference)
//
#include <hip/hip_runtime.h>
#include <math.h>

#define HID 64
#define NLAY 5
#define NFF 512

// Broadcast lane k's value to all 64 lanes via v_readlane (k is wave-uniform).
__device__ __forceinline__ float bcastf(float v, int lane) {
  return __int_as_float(__builtin_amdgcn_readlane(__float_as_int(v), lane));
}

// fp32 -> bf16 (round-to-nearest-even), bit trick; and back.
__device__ __forceinline__ unsigned short f2bf(float x) {
  unsigned int b = __float_as_uint(x);
  b += 0x7FFFu + ((b >> 16) & 1u);
  return (unsigned short)(b >> 16);
}
__device__ __forceinline__ float bf2f(unsigned short u) {
  return __uint_as_float((unsigned int)u << 16);
}

// Wl[l] = edge_emb_w (4x64) @ edge_lin_w[l] (64x64)  -> [4][64] per layer
__global__ void prep_wl_kernel(const float* __restrict__ edge_emb_w,
                               const float* __restrict__ edge_lin_w,
                               float* __restrict__ Wl) {
  int l = blockIdx.x;
  int t = threadIdx.x;       // 256 threads = 4 j-rows x 64 dims
  int j = t >> 6;
  int d = t & 63;
  const float* ew = edge_emb_w + j * HID;
  const float* lw = edge_lin_w + l * HID * HID;
  float acc = 0.f;
#pragma unroll
  for (int k = 0; k < HID; ++k) acc = fmaf(ew[k], lw[k * HID + d], acc);
  Wl[(l * 4 + j) * HID + d] = acc;
}

// h[n][d] = vert_emb[x[n]][d] ; also bf16 shadow for the gather path.
__global__ void embed_kernel(const int* __restrict__ x,
                             const float* __restrict__ vert_emb,
                             float* __restrict__ h,
                             unsigned short* __restrict__ h16, int n) {
  int idx = blockIdx.x * blockDim.x + threadIdx.x;
  if (idx >= n * HID) return;
  int node = idx >> 6;
  int d = idx & 63;
  float v = vert_emb[x[node] * HID + d];
  h[idx] = v;
  h16[idx] = f2bf(v);
}

// ---- CSR build (once per call, reused across 5 layers) ----

__global__ void zero_deg_kernel(int* __restrict__ deg, int n) {
  int i = blockIdx.x * blockDim.x + threadIdx.x;
  if (i < n) deg[i] = 0;
}

__global__ void hist_kernel(const int* __restrict__ dst, int* __restrict__ deg, int E) {
  int e = blockIdx.x * blockDim.x + threadIdx.x;
  if (e < E) atomicAdd(&deg[dst[e]], 1);
}

// Multi-block exclusive scan, phase 1: per-block sums.
__global__ void bsum_kernel(const int* __restrict__ deg, int* __restrict__ bsum, int n) {
  __shared__ int s[256];
  int t = threadIdx.x;
  int i = blockIdx.x * 256 + t;
  s[t] = (i < n) ? deg[i] : 0;
  __syncthreads();
#pragma unroll
  for (int off = 128; off > 0; off >>= 1) {
    if (t < off) s[t] += s[t + off];
    __syncthreads();
  }
  if (t == 0) bsum[blockIdx.x] = s[0];
}

// Phase 2: one block scans the block sums -> exclusive offsets.
__global__ void bscan_kernel(const int* __restrict__ bsum, int* __restrict__ boff, int nb) {
  __shared__ int s[256];
  int t = threadIdx.x;
  int v = (t < nb) ? bsum[t] : 0;
  s[t] = v;
  __syncthreads();
#pragma unroll
  for (int off = 1; off < 256; off <<= 1) {
    int u = (t >= off) ? s[t - off] : 0;
    __syncthreads();
    s[t] += u;
    __syncthreads();
  }
  if (t < nb) boff[t] = s[t] - v;   // exclusive
}

// Phase 3: per-block scan + offset -> row_ptr, cursor; last element writes row_ptr[n].
__global__ void scan3_kernel(const int* __restrict__ deg, const int* __restrict__ boff,
                             int* __restrict__ row_ptr, int* __restrict__ cursor, int n) {
  __shared__ int s[256];
  int t = threadIdx.x;
  int i = blockIdx.x * 256 + t;
  int v = (i < n) ? deg[i] : 0;
  s[t] = v;
  __syncthreads();
#pragma unroll
  for (int off = 1; off < 256; off <<= 1) {
    int u = (t >= off) ? s[t - off] : 0;
    __syncthreads();
    s[t] += u;
    __syncthreads();
  }
  if (i < n) {
    int excl = boff[blockIdx.x] + s[t] - v;
    row_ptr[i] = excl;
    cursor[i] = excl;
    if (i == n - 1) row_ptr[n] = excl + v;
  }
}

__global__ void scatter_kernel(const int* __restrict__ src,
                               const int* __restrict__ dst,
                               const float4* __restrict__ edge_attr,
                               int* __restrict__ cursor,
                               int* __restrict__ csr_src,
                               float4* __restrict__ csr_ea, int E) {
  int e = blockIdx.x * blockDim.x + threadIdx.x;
  if (e >= E) return;
  int pos = atomicAdd(&cursor[dst[e]], 1);
  csr_src[pos] = src[e];
  csr_ea[pos] = edge_attr[e];
}

// ---- gather: 1 wave per dst node, lane = dim, bf16 h payload ----
// Rank-4 form: P_r[d] = sum_j ea_j[r]*h[src_j][d]; agg = sum_r Wl[r][d]*P_r[d].
__global__ __launch_bounds__(256, 8)
void gather_kernel(const int* __restrict__ row_ptr,
                   const int* __restrict__ csr_src,
                   const float4* __restrict__ csr_ea,
                   const float* __restrict__ Wl,   // [4][64]
                   const unsigned short* __restrict__ h16,
                   float* __restrict__ agg, int n) {
  int wid = threadIdx.x >> 6;
  int d = threadIdx.x & 63;
  int node = blockIdx.x * 4 + wid;
  if (node >= n) return;
  int beg = __builtin_amdgcn_readfirstlane(row_ptr[node]);
  int end = __builtin_amdgcn_readfirstlane(row_ptr[node + 1]);
  float P0 = 0.f, P1 = 0.f, P2 = 0.f, P3 = 0.f;
  int j = beg;
  for (; j + 16 <= end; j += 16) {
    int ss[16];
    float hh[16];
    float4 ee[16];
#pragma unroll
    for (int u = 0; u < 16; ++u) ss[u] = csr_src[j + u];
#pragma unroll
    for (int u = 0; u < 16; ++u) hh[u] = bf2f(h16[(size_t)ss[u] * HID + d]);
#pragma unroll
    for (int u = 0; u < 16; ++u) ee[u] = csr_ea[j + u];   // uniform -> s_load
#pragma unroll
    for (int u = 0; u < 16; ++u) {
      P0 = fmaf(ee[u].x, hh[u], P0);
      P1 = fmaf(ee[u].y, hh[u], P1);
      P2 = fmaf(ee[u].z, hh[u], P2);
      P3 = fmaf(ee[u].w, hh[u], P3);
    }
  }
  for (; j + 4 <= end; j += 4) {
    int ss[4];
    float hh[4];
    float4 ee[4];
#pragma unroll
    for (int u = 0; u < 4; ++u) ss[u] = csr_src[j + u];
#pragma unroll
    for (int u = 0; u < 4; ++u) hh[u] = bf2f(h16[(size_t)ss[u] * HID + d]);
#pragma unroll
    for (int u = 0; u < 4; ++u) ee[u] = csr_ea[j + u];
#pragma unroll
    for (int u = 0; u < 4; ++u) {
      P0 = fmaf(ee[u].x, hh[u], P0);
      P1 = fmaf(ee[u].y, hh[u], P1);
      P2 = fmaf(ee[u].z, hh[u], P2);
      P3 = fmaf(ee[u].w, hh[u], P3);
    }
  }
  for (; j < end; ++j) {
    int s0 = csr_src[j];
    float4 e0 = csr_ea[j];
    float h0 = bf2f(h16[(size_t)s0 * HID + d]);
    P0 = fmaf(e0.x, h0, P0);
    P1 = fmaf(e0.y, h0, P1);
    P2 = fmaf(e0.z, h0, P2);
    P3 = fmaf(e0.w, h0, P3);
  }
  float acc = P0 * Wl[d];
  acc = fmaf(P1, Wl[HID + d], acc);
  acc = fmaf(P2, Wl[2 * HID + d], acc);
  acc = fmaf(P3, Wl[3 * HID + d], acc);
  agg[(size_t)node * HID + d] = acc;
}

// hn = relu(agg@rel_w + rel_b + h@root_w) + h@res_w ; 8 nodes per wave.
// Also writes the bf16 shadow of hn for the next layer's gather.
__global__ __launch_bounds__(256, 8)
void node_kernel(const float* __restrict__ h,
                 const float* __restrict__ agg,
                 const float* __restrict__ rel_w,
                 const float* __restrict__ rel_b,
                 const float* __restrict__ root_w,
                 const float* __restrict__ res_w,
                 float* __restrict__ hn,
                 unsigned short* __restrict__ hn16, int n) {
  int wid = threadIdx.x >> 6;
  int d = threadIdx.x & 63;
  int base = (blockIdx.x * 4 + wid) * 8;
  if (base >= n) return;
  float bd = rel_b[d];
  float hval[8], aval[8], acc2[8], accR[8];
#pragma unroll
  for (int i = 0; i < 8; ++i) {
    int node = base + i;
    bool ok = node < n;
    hval[i] = ok ? h[(size_t)node * HID + d] : 0.f;
    aval[i] = ok ? agg[(size_t)node * HID + d] : 0.f;
    acc2[i] = bd;
    accR[i] = 0.f;
  }
#pragma unroll 8
  for (int k = 0; k < HID; ++k) {
    float wr = rel_w[k * HID + d];
    float wo = root_w[k * HID + d];
    float wq = res_w[k * HID + d];
#pragma unroll
    for (int i = 0; i < 8; ++i) {
      float hk = bcastf(hval[i], k);
      float ak = bcastf(aval[i], k);
      acc2[i] = fmaf(ak, wr, acc2[i]);
      acc2[i] = fmaf(hk, wo, acc2[i]);
      accR[i] = fmaf(hk, wq, accR[i]);
    }
  }
#pragma unroll
  for (int i = 0; i < 8; ++i) {
    int node = base + i;
    if (node < n) {
      float v = fmaxf(acc2[i], 0.f) + accR[i];
      hn[(size_t)node * HID + d] = v;
      hn16[(size_t)node * HID + d] = f2bf(v);
    }
  }
}

// out[n] = b2 + sum_f gelu(h[n]@w1[:,f] + b1[f]) * w2[f] ; 8 nodes per wave.
// w1 staged in LDS in four 16x512 tiles (32 KB): per-wave L2 streaming of the
// whole 128 KB w1 (6250 waves x 128 KB = 800 MB) becomes per-block (200 MB),
// and compute reads are conflict-free ds_read_b32 (addr = lane + c*64: 2
// lanes/bank = free). Feature mapping f = c*64 + lane.
// NOTE: no early return -- all threads must reach the barriers.
__global__ __launch_bounds__(256, 2)
void head_kernel(const float* __restrict__ h,
                 const float4* __restrict__ w1v,  // [64][128] float4
                 const float* __restrict__ b1,    // [512]
                 const float* __restrict__ w2,    // [512]
                 const float* __restrict__ b2,
                 float* __restrict__ out, int n) {
  __shared__ float lw1[16 * NFF];   // 32 KB tile
  int tid = threadIdx.x;
  int wid = tid >> 6;
  int lane = tid & 63;
  int base = (blockIdx.x * 4 + wid) * 8;
  float hval[8];
#pragma unroll
  for (int i = 0; i < 8; ++i)
    hval[i] = (base + i < n) ? h[(size_t)(base + i) * HID + lane] : 0.f;
  float acc[8][8];
#pragma unroll
  for (int i = 0; i < 8; ++i)
#pragma unroll
    for (int c = 0; c < 8; ++c) acc[i][c] = 0.f;
  for (int t = 0; t < 4; ++t) {
    int k0 = t * 16;
    __syncthreads();   // previous tile fully consumed
#pragma unroll
    for (int q = 0; q < 8; ++q)
      ((float4*)lw1)[q * 256 + tid] = w1v[k0 * (NFF / 4) + q * 256 + tid];
    __syncthreads();
#pragma unroll 2
    for (int kk = 0; kk < 16; ++kk) {
      float wv[8];
#pragma unroll
      for (int c = 0; c < 8; ++c) wv[c] = lw1[kk * NFF + c * 64 + lane];
#pragma unroll
      for (int i = 0; i < 8; ++i) {
        float hk = bcastf(hval[i], k0 + kk);
#pragma unroll
        for (int c = 0; c < 8; ++c) acc[i][c] = fmaf(hk, wv[c], acc[i][c]);
      }
    }
  }
  float bbuf[8], wbuf[8];
#pragma unroll
  for (int c = 0; c < 8; ++c) {
    bbuf[c] = b1[c * 64 + lane];
    wbuf[c] = w2[c * 64 + lane];
  }
  float partial[8];
#pragma unroll
  for (int i = 0; i < 8; ++i) partial[i] = 0.f;
#pragma unroll
  for (int c = 0; c < 8; ++c) {
#pragma unroll
    for (int i = 0; i < 8; ++i) {
      float xv = acc[i][c] + bbuf[c];
      float g = 0.5f * xv * (1.f + erff(xv * 0.70710678118654752f)); // exact GELU
      partial[i] = fmaf(g, wbuf[c], partial[i]);
    }
  }
#pragma unroll
  for (int i = 0; i < 8; ++i) {
#pragma unroll
    for (int off = 32; off > 0; off >>= 1)
      partial[i] += __shfl_xor(partial[i], off);
  }
  if (lane == 0) {
    float bias = b2[0];
#pragma unroll
    for (int i = 0; i < 8; ++i)
      if (base + i < n) out[base + i] = partial[i] + bias;
  }
}

extern "C" void kernel_launch(void* const* d_in, const int* in_sizes, int n_in,
                              void* d_out, int out_size, void* d_ws, size_t ws_size,
                              hipStream_t stream) {
  const int*   x          = (const int*)d_in[0];
  const int*   edge_index = (const int*)d_in[1];
  const float* edge_attr  = (const float*)d_in[2];
  const float* vert_emb   = (const float*)d_in[3];
  const float* edge_emb_w = (const float*)d_in[4];
  const float* edge_lin_w = (const float*)d_in[5];
  const float* rel_w      = (const float*)d_in[6];
  const float* rel_b      = (const float*)d_in[7];
  const float* root_w     = (const float*)d_in[8];
  const float* res_w      = (const float*)d_in[9];
  const float* w1         = (const float*)d_in[10];
  const float* b1         = (const float*)d_in[11];
  const float* w2         = (const float*)d_in[12];
  const float* b2         = (const float*)d_in[13];

  const int n = in_sizes[0];
  const int E = in_sizes[2] / 4;
  const int* src = edge_index;
  const int* dst = edge_index + E;
  const int nb = (n + 255) / 256;   // scan blocks (196 for n=50000)

  // workspace layout:
  //   Wl[2048] f | hA[n*64] f | hB[n*64] f | agg[n*64] f | csr_ea[E] float4 |
  //   csr_src[E] int | row_ptr[n+1] int | cursor[n] int | deg[n] int |
  //   bsum[256] int | boff[256] int | h16A[n*64] u16 | h16B[n*64] u16
  float* ws   = (float*)d_ws;
  float* Wl   = ws;
  float* hA   = ws + 2048;
  float* hB   = hA + (size_t)n * HID;
  float* agg  = hB + (size_t)n * HID;
  float4* csr_ea = (float4*)(agg + (size_t)n * HID);
  int* csr_src = (int*)(csr_ea + (size_t)E);
  int* row_ptr = csr_src + E;
  int* cursor  = row_ptr + (n + 1);
  int* deg     = cursor + n;
  int* bsum    = deg + n;
  int* boff    = bsum + 256;
  unsigned short* h16A = (unsigned short*)(boff + 256);
  unsigned short* h16B = h16A + (size_t)n * HID;

  prep_wl_kernel<<<dim3(NLAY), dim3(256), 0, stream>>>(edge_emb_w, edge_lin_w, Wl);

  int totalHD = n * HID;
  embed_kernel<<<dim3((totalHD + 255) / 256), dim3(256), 0, stream>>>(
      x, vert_emb, hA, h16A, n);

  // CSR build (amortized over 5 layers)
  zero_deg_kernel<<<dim3((n + 255) / 256), dim3(256), 0, stream>>>(deg, n);
  hist_kernel<<<dim3((E + 255) / 256), dim3(256), 0, stream>>>(dst, deg, E);
  bsum_kernel<<<dim3(nb), dim3(256), 0, stream>>>(deg, bsum, n);
  bscan_kernel<<<dim3(1), dim3(256), 0, stream>>>(bsum, boff, nb);
  scan3_kernel<<<dim3(nb), dim3(256), 0, stream>>>(deg, boff, row_ptr, cursor, n);
  scatter_kernel<<<dim3((E + 255) / 256), dim3(256), 0, stream>>>(
      src, dst, (const float4*)edge_attr, cursor, csr_src, csr_ea, E);

  float* hc = hA;
  float* hx = hB;
  unsigned short* h16c = h16A;
  unsigned short* h16x = h16B;
  for (int l = 0; l < NLAY; ++l) {
    gather_kernel<<<dim3((n + 3) / 4), dim3(256), 0, stream>>>(
        row_ptr, csr_src, csr_ea, Wl + l * 4 * HID, h16c, agg, n);
    node_kernel<<<dim3((n + 31) / 32), dim3(256), 0, stream>>>(
        hc, agg, rel_w + l * HID * HID, rel_b + l * HID,
        root_w + l * HID * HID, res_w + l * HID * HID, hx, h16x, n);
    float* t = hc; hc = hx; hx = t;
    unsigned short* t16 = h16c; h16c = h16x; h16x = t16;
  }

  head_kernel<<<dim3((n + 31) / 32), dim3(256), 0, stream>>>(
      hc, (const float4*)w1, b1, w2, b2, (float*)d_out, n);
}

// Round 11
// 564.702 us; speedup vs baseline: 1.0462x; 1.0462x over previous
//
#include <hip/hip_runtime.h>
#include <math.h>

#define HID 64
#define NLAY 5
#define NFF 512

// Broadcast lane k's value to all 64 lanes via v_readlane (k is wave-uniform).
__device__ __forceinline__ float bcastf(float v, int lane) {
  return __int_as_float(__builtin_amdgcn_readlane(__float_as_int(v), lane));
}

// fp32 -> bf16 (round-to-nearest-even), bit trick; and back.
__device__ __forceinline__ unsigned short f2bf(float x) {
  unsigned int b = __float_as_uint(x);
  b += 0x7FFFu + ((b >> 16) & 1u);
  return (unsigned short)(b >> 16);
}
__device__ __forceinline__ float bf2f(unsigned short u) {
  return __uint_as_float((unsigned int)u << 16);
}

// Wl[l] = edge_emb_w (4x64) @ edge_lin_w[l] (64x64)  -> [4][64] per layer
__global__ void prep_wl_kernel(const float* __restrict__ edge_emb_w,
                               const float* __restrict__ edge_lin_w,
                               float* __restrict__ Wl) {
  int l = blockIdx.x;
  int t = threadIdx.x;       // 256 threads = 4 j-rows x 64 dims
  int j = t >> 6;
  int d = t & 63;
  const float* ew = edge_emb_w + j * HID;
  const float* lw = edge_lin_w + l * HID * HID;
  float acc = 0.f;
#pragma unroll
  for (int k = 0; k < HID; ++k) acc = fmaf(ew[k], lw[k * HID + d], acc);
  Wl[(l * 4 + j) * HID + d] = acc;
}

// h[n][d] = vert_emb[x[n]][d] ; also bf16 shadow for the gather path.
__global__ void embed_kernel(const int* __restrict__ x,
                             const float* __restrict__ vert_emb,
                             float* __restrict__ h,
                             unsigned short* __restrict__ h16, int n) {
  int idx = blockIdx.x * blockDim.x + threadIdx.x;
  if (idx >= n * HID) return;
  int node = idx >> 6;
  int d = idx & 63;
  float v = vert_emb[x[node] * HID + d];
  h[idx] = v;
  h16[idx] = f2bf(v);
}

// ---- CSR build (once per call, reused across 5 layers) ----

__global__ void zero_deg_kernel(int* __restrict__ deg, int n) {
  int i = blockIdx.x * blockDim.x + threadIdx.x;
  if (i < n) deg[i] = 0;
}

__global__ void hist_kernel(const int* __restrict__ dst, int* __restrict__ deg, int E) {
  int e = blockIdx.x * blockDim.x + threadIdx.x;
  if (e < E) atomicAdd(&deg[dst[e]], 1);
}

// Multi-block exclusive scan, phase 1: per-block sums.
__global__ void bsum_kernel(const int* __restrict__ deg, int* __restrict__ bsum, int n) {
  __shared__ int s[256];
  int t = threadIdx.x;
  int i = blockIdx.x * 256 + t;
  s[t] = (i < n) ? deg[i] : 0;
  __syncthreads();
#pragma unroll
  for (int off = 128; off > 0; off >>= 1) {
    if (t < off) s[t] += s[t + off];
    __syncthreads();
  }
  if (t == 0) bsum[blockIdx.x] = s[0];
}

// Phase 2: one block scans the block sums -> exclusive offsets.
__global__ void bscan_kernel(const int* __restrict__ bsum, int* __restrict__ boff, int nb) {
  __shared__ int s[256];
  int t = threadIdx.x;
  int v = (t < nb) ? bsum[t] : 0;
  s[t] = v;
  __syncthreads();
#pragma unroll
  for (int off = 1; off < 256; off <<= 1) {
    int u = (t >= off) ? s[t - off] : 0;
    __syncthreads();
    s[t] += u;
    __syncthreads();
  }
  if (t < nb) boff[t] = s[t] - v;   // exclusive
}

// Phase 3: per-block scan + offset -> row_ptr, cursor; last element writes row_ptr[n].
__global__ void scan3_kernel(const int* __restrict__ deg, const int* __restrict__ boff,
                             int* __restrict__ row_ptr, int* __restrict__ cursor, int n) {
  __shared__ int s[256];
  int t = threadIdx.x;
  int i = blockIdx.x * 256 + t;
  int v = (i < n) ? deg[i] : 0;
  s[t] = v;
  __syncthreads();
#pragma unroll
  for (int off = 1; off < 256; off <<= 1) {
    int u = (t >= off) ? s[t - off] : 0;
    __syncthreads();
    s[t] += u;
    __syncthreads();
  }
  if (i < n) {
    int excl = boff[blockIdx.x] + s[t] - v;
    row_ptr[i] = excl;
    cursor[i] = excl;
    if (i == n - 1) row_ptr[n] = excl + v;
  }
}

__global__ void scatter_kernel(const int* __restrict__ src,
                               const int* __restrict__ dst,
                               const float4* __restrict__ edge_attr,
                               int* __restrict__ cursor,
                               int* __restrict__ csr_src,
                               float4* __restrict__ csr_ea, int E) {
  int e = blockIdx.x * blockDim.x + threadIdx.x;
  if (e >= E) return;
  int pos = atomicAdd(&cursor[dst[e]], 1);
  csr_src[pos] = src[e];
  csr_ea[pos] = edge_attr[e];
}

// ---- gather: 1 wave per dst node, lane = dim, bf16 h payload ----
// Rank-4 form: P_r[d] = sum_j ea_j[r]*h[src_j][d]; agg = sum_r Wl[r][d]*P_r[d].
__global__ __launch_bounds__(256, 8)
void gather_kernel(const int* __restrict__ row_ptr,
                   const int* __restrict__ csr_src,
                   const float4* __restrict__ csr_ea,
                   const float* __restrict__ Wl,   // [4][64]
                   const unsigned short* __restrict__ h16,
                   float* __restrict__ agg, int n) {
  int wid = threadIdx.x >> 6;
  int d = threadIdx.x & 63;
  int node = blockIdx.x * 4 + wid;
  if (node >= n) return;
  int beg = __builtin_amdgcn_readfirstlane(row_ptr[node]);
  int end = __builtin_amdgcn_readfirstlane(row_ptr[node + 1]);
  float P0 = 0.f, P1 = 0.f, P2 = 0.f, P3 = 0.f;
  int j = beg;
  for (; j + 16 <= end; j += 16) {
    int ss[16];
    float hh[16];
    float4 ee[16];
#pragma unroll
    for (int u = 0; u < 16; ++u) ss[u] = csr_src[j + u];
#pragma unroll
    for (int u = 0; u < 16; ++u) hh[u] = bf2f(h16[(size_t)ss[u] * HID + d]);
#pragma unroll
    for (int u = 0; u < 16; ++u) ee[u] = csr_ea[j + u];   // uniform -> s_load
#pragma unroll
    for (int u = 0; u < 16; ++u) {
      P0 = fmaf(ee[u].x, hh[u], P0);
      P1 = fmaf(ee[u].y, hh[u], P1);
      P2 = fmaf(ee[u].z, hh[u], P2);
      P3 = fmaf(ee[u].w, hh[u], P3);
    }
  }
  for (; j + 4 <= end; j += 4) {
    int ss[4];
    float hh[4];
    float4 ee[4];
#pragma unroll
    for (int u = 0; u < 4; ++u) ss[u] = csr_src[j + u];
#pragma unroll
    for (int u = 0; u < 4; ++u) hh[u] = bf2f(h16[(size_t)ss[u] * HID + d]);
#pragma unroll
    for (int u = 0; u < 4; ++u) ee[u] = csr_ea[j + u];
#pragma unroll
    for (int u = 0; u < 4; ++u) {
      P0 = fmaf(ee[u].x, hh[u], P0);
      P1 = fmaf(ee[u].y, hh[u], P1);
      P2 = fmaf(ee[u].z, hh[u], P2);
      P3 = fmaf(ee[u].w, hh[u], P3);
    }
  }
  for (; j < end; ++j) {
    int s0 = csr_src[j];
    float4 e0 = csr_ea[j];
    float h0 = bf2f(h16[(size_t)s0 * HID + d]);
    P0 = fmaf(e0.x, h0, P0);
    P1 = fmaf(e0.y, h0, P1);
    P2 = fmaf(e0.z, h0, P2);
    P3 = fmaf(e0.w, h0, P3);
  }
  float acc = P0 * Wl[d];
  acc = fmaf(P1, Wl[HID + d], acc);
  acc = fmaf(P2, Wl[2 * HID + d], acc);
  acc = fmaf(P3, Wl[3 * HID + d], acc);
  agg[(size_t)node * HID + d] = acc;
}

// hn = relu(agg@rel_w + rel_b + h@root_w) + h@res_w ; 8 nodes per wave.
// Also writes the bf16 shadow of hn for the next layer's gather.
__global__ __launch_bounds__(256, 8)
void node_kernel(const float* __restrict__ h,
                 const float* __restrict__ agg,
                 const float* __restrict__ rel_w,
                 const float* __restrict__ rel_b,
                 const float* __restrict__ root_w,
                 const float* __restrict__ res_w,
                 float* __restrict__ hn,
                 unsigned short* __restrict__ hn16, int n) {
  int wid = threadIdx.x >> 6;
  int d = threadIdx.x & 63;
  int base = (blockIdx.x * 4 + wid) * 8;
  if (base >= n) return;
  float bd = rel_b[d];
  float hval[8], aval[8], acc2[8], accR[8];
#pragma unroll
  for (int i = 0; i < 8; ++i) {
    int node = base + i;
    bool ok = node < n;
    hval[i] = ok ? h[(size_t)node * HID + d] : 0.f;
    aval[i] = ok ? agg[(size_t)node * HID + d] : 0.f;
    acc2[i] = bd;
    accR[i] = 0.f;
  }
#pragma unroll 8
  for (int k = 0; k < HID; ++k) {
    float wr = rel_w[k * HID + d];
    float wo = root_w[k * HID + d];
    float wq = res_w[k * HID + d];
#pragma unroll
    for (int i = 0; i < 8; ++i) {
      float hk = bcastf(hval[i], k);
      float ak = bcastf(aval[i], k);
      acc2[i] = fmaf(ak, wr, acc2[i]);
      acc2[i] = fmaf(hk, wo, acc2[i]);
      accR[i] = fmaf(hk, wq, accR[i]);
    }
  }
#pragma unroll
  for (int i = 0; i < 8; ++i) {
    int node = base + i;
    if (node < n) {
      float v = fmaxf(acc2[i], 0.f) + accR[i];
      hn[(size_t)node * HID + d] = v;
      hn16[(size_t)node * HID + d] = f2bf(v);
    }
  }
}

// out[n] = b2 + sum_f gelu(h[n]@w1[:,f] + b1[f]) * w2[f] ; 4 nodes per wave.
// Head is VALU-issue/stall-bound at ~6 waves/SIMD (r10: LDS staging regressed,
// L2 traffic was never the limit). 4 nodes/wave doubles wave count (12500,
// ~12/SIMD) to hide per-instr stalls; live state ~65 VGPR, LB(256,4) -> no spill.
// Feature mapping: f = lane*8 + c -> w1 row loads are two coalesced float4s.
__global__ __launch_bounds__(256, 4)
void head_kernel(const float* __restrict__ h,
                 const float4* __restrict__ w1v,  // [64][128] float4
                 const float4* __restrict__ b1v,  // [128] float4
                 const float4* __restrict__ w2v,  // [128] float4
                 const float* __restrict__ b2,
                 float* __restrict__ out, int n) {
  int wid = threadIdx.x >> 6;
  int lane = threadIdx.x & 63;
  int base = (blockIdx.x * 4 + wid) * 4;
  if (base >= n) return;
  float hval[4];
#pragma unroll
  for (int i = 0; i < 4; ++i)
    hval[i] = (base + i < n) ? h[(size_t)(base + i) * HID + lane] : 0.f;
  float acc[4][8];
#pragma unroll
  for (int i = 0; i < 4; ++i)
#pragma unroll
    for (int c = 0; c < 8; ++c) acc[i][c] = 0.f;
#pragma unroll 4
  for (int k = 0; k < HID; ++k) {
    float4 wa = w1v[k * (NFF / 4) + lane * 2];
    float4 wb = w1v[k * (NFF / 4) + lane * 2 + 1];
#pragma unroll
    for (int i = 0; i < 4; ++i) {
      float hk = bcastf(hval[i], k);
      acc[i][0] = fmaf(hk, wa.x, acc[i][0]);
      acc[i][1] = fmaf(hk, wa.y, acc[i][1]);
      acc[i][2] = fmaf(hk, wa.z, acc[i][2]);
      acc[i][3] = fmaf(hk, wa.w, acc[i][3]);
      acc[i][4] = fmaf(hk, wb.x, acc[i][4]);
      acc[i][5] = fmaf(hk, wb.y, acc[i][5]);
      acc[i][6] = fmaf(hk, wb.z, acc[i][6]);
      acc[i][7] = fmaf(hk, wb.w, acc[i][7]);
    }
  }
  float4 ba = b1v[lane * 2], bb = b1v[lane * 2 + 1];
  float4 va = w2v[lane * 2], vb = w2v[lane * 2 + 1];
  float bbuf[8] = {ba.x, ba.y, ba.z, ba.w, bb.x, bb.y, bb.z, bb.w};
  float wbuf[8] = {va.x, va.y, va.z, va.w, vb.x, vb.y, vb.z, vb.w};
  float partial[4];
#pragma unroll
  for (int i = 0; i < 4; ++i) partial[i] = 0.f;
#pragma unroll
  for (int c = 0; c < 8; ++c) {
#pragma unroll
    for (int i = 0; i < 4; ++i) {
      float xv = acc[i][c] + bbuf[c];
      float g = 0.5f * xv * (1.f + erff(xv * 0.70710678118654752f)); // exact GELU
      partial[i] = fmaf(g, wbuf[c], partial[i]);
    }
  }
#pragma unroll
  for (int i = 0; i < 4; ++i) {
#pragma unroll
    for (int off = 32; off > 0; off >>= 1)
      partial[i] += __shfl_xor(partial[i], off);
  }
  if (lane == 0) {
    float bias = b2[0];
#pragma unroll
    for (int i = 0; i < 4; ++i)
      if (base + i < n) out[base + i] = partial[i] + bias;
  }
}

extern "C" void kernel_launch(void* const* d_in, const int* in_sizes, int n_in,
                              void* d_out, int out_size, void* d_ws, size_t ws_size,
                              hipStream_t stream) {
  const int*   x          = (const int*)d_in[0];
  const int*   edge_index = (const int*)d_in[1];
  const float* edge_attr  = (const float*)d_in[2];
  const float* vert_emb   = (const float*)d_in[3];
  const float* edge_emb_w = (const float*)d_in[4];
  const float* edge_lin_w = (const float*)d_in[5];
  const float* rel_w      = (const float*)d_in[6];
  const float* rel_b      = (const float*)d_in[7];
  const float* root_w     = (const float*)d_in[8];
  const float* res_w      = (const float*)d_in[9];
  const float* w1         = (const float*)d_in[10];
  const float* b1         = (const float*)d_in[11];
  const float* w2         = (const float*)d_in[12];
  const float* b2         = (const float*)d_in[13];

  const int n = in_sizes[0];
  const int E = in_sizes[2] / 4;
  const int* src = edge_index;
  const int* dst = edge_index + E;
  const int nb = (n + 255) / 256;   // scan blocks (196 for n=50000)

  // workspace layout:
  //   Wl[2048] f | hA[n*64] f | hB[n*64] f | agg[n*64] f | csr_ea[E] float4 |
  //   csr_src[E] int | row_ptr[n+1] int | cursor[n] int | deg[n] int |
  //   bsum[256] int | boff[256] int | h16A[n*64] u16 | h16B[n*64] u16
  float* ws   = (float*)d_ws;
  float* Wl   = ws;
  float* hA   = ws + 2048;
  float* hB   = hA + (size_t)n * HID;
  float* agg  = hB + (size_t)n * HID;
  float4* csr_ea = (float4*)(agg + (size_t)n * HID);
  int* csr_src = (int*)(csr_ea + (size_t)E);
  int* row_ptr = csr_src + E;
  int* cursor  = row_ptr + (n + 1);
  int* deg     = cursor + n;
  int* bsum    = deg + n;
  int* boff    = bsum + 256;
  unsigned short* h16A = (unsigned short*)(boff + 256);
  unsigned short* h16B = h16A + (size_t)n * HID;

  prep_wl_kernel<<<dim3(NLAY), dim3(256), 0, stream>>>(edge_emb_w, edge_lin_w, Wl);

  int totalHD = n * HID;
  embed_kernel<<<dim3((totalHD + 255) / 256), dim3(256), 0, stream>>>(
      x, vert_emb, hA, h16A, n);

  // CSR build (amortized over 5 layers)
  zero_deg_kernel<<<dim3((n + 255) / 256), dim3(256), 0, stream>>>(deg, n);
  hist_kernel<<<dim3((E + 255) / 256), dim3(256), 0, stream>>>(dst, deg, E);
  bsum_kernel<<<dim3(nb), dim3(256), 0, stream>>>(deg, bsum, n);
  bscan_kernel<<<dim3(1), dim3(256), 0, stream>>>(bsum, boff, nb);
  scan3_kernel<<<dim3(nb), dim3(256), 0, stream>>>(deg, boff, row_ptr, cursor, n);
  scatter_kernel<<<dim3((E + 255) / 256), dim3(256), 0, stream>>>(
      src, dst, (const float4*)edge_attr, cursor, csr_src, csr_ea, E);

  float* hc = hA;
  float* hx = hB;
  unsigned short* h16c = h16A;
  unsigned short* h16x = h16B;
  for (int l = 0; l < NLAY; ++l) {
    gather_kernel<<<dim3((n + 3) / 4), dim3(256), 0, stream>>>(
        row_ptr, csr_src, csr_ea, Wl + l * 4 * HID, h16c, agg, n);
    node_kernel<<<dim3((n + 31) / 32), dim3(256), 0, stream>>>(
        hc, agg, rel_w + l * HID * HID, rel_b + l * HID,
        root_w + l * HID * HID, res_w + l * HID * HID, hx, h16x, n);
    float* t = hc; hc = hx; hx = t;
    unsigned short* t16 = h16c; h16c = h16x; h16x = t16;
  }

  head_kernel<<<dim3((n + 15) / 16), dim3(256), 0, stream>>>(
      hc, (const float4*)w1, (const float4*)b1, (const float4*)w2, b2,
      (float*)d_out, n);
}

// Round 12
// 535.543 us; speedup vs baseline: 1.1032x; 1.0544x over previous
//
#include <hip/hip_runtime.h>
#include <math.h>

#define HID 64
#define NLAY 5
#define NFF 512

typedef __attribute__((ext_vector_type(8))) short bf16x8;
typedef __attribute__((ext_vector_type(4))) float f32x4;

// Broadcast lane k's value to all 64 lanes via v_readlane (k is wave-uniform).
__device__ __forceinline__ float bcastf(float v, int lane) {
  return __int_as_float(__builtin_amdgcn_readlane(__float_as_int(v), lane));
}

// fp32 -> bf16 (round-to-nearest-even), bit trick; and back.
__device__ __forceinline__ unsigned short f2bf(float x) {
  unsigned int b = __float_as_uint(x);
  b += 0x7FFFu + ((b >> 16) & 1u);
  return (unsigned short)(b >> 16);
}
__device__ __forceinline__ float bf2f(unsigned short u) {
  return __uint_as_float((unsigned int)u << 16);
}

// Wl[l] = edge_emb_w (4x64) @ edge_lin_w[l] (64x64)  -> [4][64] per layer
__global__ void prep_wl_kernel(const float* __restrict__ edge_emb_w,
                               const float* __restrict__ edge_lin_w,
                               float* __restrict__ Wl) {
  int l = blockIdx.x;
  int t = threadIdx.x;       // 256 threads = 4 j-rows x 64 dims
  int j = t >> 6;
  int d = t & 63;
  const float* ew = edge_emb_w + j * HID;
  const float* lw = edge_lin_w + l * HID * HID;
  float acc = 0.f;
#pragma unroll
  for (int k = 0; k < HID; ++k) acc = fmaf(ew[k], lw[k * HID + d], acc);
  Wl[(l * 4 + j) * HID + d] = acc;
}

// Split w1 into bf16 hi/lo MFMA B-fragments (one-time).
// Frag f = kt*32 + nt (kt: k-tile of 32, nt: 16-col tile). Lane l holds
// B[kt*32 + (l>>4)*8 + j][nt*16 + (l&15)], j=0..7, stored at [f*512 + l*8].
__global__ void prep_w1b_kernel(const float* __restrict__ w1,
                                unsigned short* __restrict__ w1bhi,
                                unsigned short* __restrict__ w1blo) {
  int t = blockIdx.x * 256 + threadIdx.x;   // 0..4095
  int f = t >> 6;
  int l = t & 63;
  int kt = f >> 5;
  int nt = f & 31;
  int krow = kt * 32 + (l >> 4) * 8;
  int col = nt * 16 + (l & 15);
#pragma unroll
  for (int j = 0; j < 8; ++j) {
    float v = w1[(size_t)(krow + j) * NFF + col];
    unsigned short hi = f2bf(v);
    unsigned short lo = f2bf(v - bf2f(hi));
    w1bhi[(size_t)t * 8 + j] = hi;
    w1blo[(size_t)t * 8 + j] = lo;
  }
}

// h[n][d] = vert_emb[x[n]][d] ; also bf16 shadow for the gather path.
__global__ void embed_kernel(const int* __restrict__ x,
                             const float* __restrict__ vert_emb,
                             float* __restrict__ h,
                             unsigned short* __restrict__ h16, int n) {
  int idx = blockIdx.x * blockDim.x + threadIdx.x;
  if (idx >= n * HID) return;
  int node = idx >> 6;
  int d = idx & 63;
  float v = vert_emb[x[node] * HID + d];
  h[idx] = v;
  h16[idx] = f2bf(v);
}

// ---- CSR build (once per call, reused across 5 layers) ----

__global__ void zero_deg_kernel(int* __restrict__ deg, int n) {
  int i = blockIdx.x * blockDim.x + threadIdx.x;
  if (i < n) deg[i] = 0;
}

__global__ void hist_kernel(const int* __restrict__ dst, int* __restrict__ deg, int E) {
  int e = blockIdx.x * blockDim.x + threadIdx.x;
  if (e < E) atomicAdd(&deg[dst[e]], 1);
}

// Multi-block exclusive scan, phase 1: per-block sums.
__global__ void bsum_kernel(const int* __restrict__ deg, int* __restrict__ bsum, int n) {
  __shared__ int s[256];
  int t = threadIdx.x;
  int i = blockIdx.x * 256 + t;
  s[t] = (i < n) ? deg[i] : 0;
  __syncthreads();
#pragma unroll
  for (int off = 128; off > 0; off >>= 1) {
    if (t < off) s[t] += s[t + off];
    __syncthreads();
  }
  if (t == 0) bsum[blockIdx.x] = s[0];
}

// Phase 2: one block scans the block sums -> exclusive offsets.
__global__ void bscan_kernel(const int* __restrict__ bsum, int* __restrict__ boff, int nb) {
  __shared__ int s[256];
  int t = threadIdx.x;
  int v = (t < nb) ? bsum[t] : 0;
  s[t] = v;
  __syncthreads();
#pragma unroll
  for (int off = 1; off < 256; off <<= 1) {
    int u = (t >= off) ? s[t - off] : 0;
    __syncthreads();
    s[t] += u;
    __syncthreads();
  }
  if (t < nb) boff[t] = s[t] - v;   // exclusive
}

// Phase 3: per-block scan + offset -> row_ptr, cursor; last element writes row_ptr[n].
__global__ void scan3_kernel(const int* __restrict__ deg, const int* __restrict__ boff,
                             int* __restrict__ row_ptr, int* __restrict__ cursor, int n) {
  __shared__ int s[256];
  int t = threadIdx.x;
  int i = blockIdx.x * 256 + t;
  int v = (i < n) ? deg[i] : 0;
  s[t] = v;
  __syncthreads();
#pragma unroll
  for (int off = 1; off < 256; off <<= 1) {
    int u = (t >= off) ? s[t - off] : 0;
    __syncthreads();
    s[t] += u;
    __syncthreads();
  }
  if (i < n) {
    int excl = boff[blockIdx.x] + s[t] - v;
    row_ptr[i] = excl;
    cursor[i] = excl;
    if (i == n - 1) row_ptr[n] = excl + v;
  }
}

__global__ void scatter_kernel(const int* __restrict__ src,
                               const int* __restrict__ dst,
                               const float4* __restrict__ edge_attr,
                               int* __restrict__ cursor,
                               int* __restrict__ csr_src,
                               float4* __restrict__ csr_ea, int E) {
  int e = blockIdx.x * blockDim.x + threadIdx.x;
  if (e >= E) return;
  int pos = atomicAdd(&cursor[dst[e]], 1);
  csr_src[pos] = src[e];
  csr_ea[pos] = edge_attr[e];
}

// ---- gather: 1 wave per dst node, lane = dim, bf16 h payload ----
// Rank-4 form: P_r[d] = sum_j ea_j[r]*h[src_j][d]; agg = sum_r Wl[r][d]*P_r[d].
__global__ __launch_bounds__(256, 8)
void gather_kernel(const int* __restrict__ row_ptr,
                   const int* __restrict__ csr_src,
                   const float4* __restrict__ csr_ea,
                   const float* __restrict__ Wl,   // [4][64]
                   const unsigned short* __restrict__ h16,
                   float* __restrict__ agg, int n) {
  int wid = threadIdx.x >> 6;
  int d = threadIdx.x & 63;
  int node = blockIdx.x * 4 + wid;
  if (node >= n) return;
  int beg = __builtin_amdgcn_readfirstlane(row_ptr[node]);
  int end = __builtin_amdgcn_readfirstlane(row_ptr[node + 1]);
  float P0 = 0.f, P1 = 0.f, P2 = 0.f, P3 = 0.f;
  int j = beg;
  for (; j + 16 <= end; j += 16) {
    int ss[16];
    float hh[16];
    float4 ee[16];
#pragma unroll
    for (int u = 0; u < 16; ++u) ss[u] = csr_src[j + u];
#pragma unroll
    for (int u = 0; u < 16; ++u) hh[u] = bf2f(h16[(size_t)ss[u] * HID + d]);
#pragma unroll
    for (int u = 0; u < 16; ++u) ee[u] = csr_ea[j + u];   // uniform -> s_load
#pragma unroll
    for (int u = 0; u < 16; ++u) {
      P0 = fmaf(ee[u].x, hh[u], P0);
      P1 = fmaf(ee[u].y, hh[u], P1);
      P2 = fmaf(ee[u].z, hh[u], P2);
      P3 = fmaf(ee[u].w, hh[u], P3);
    }
  }
  for (; j + 4 <= end; j += 4) {
    int ss[4];
    float hh[4];
    float4 ee[4];
#pragma unroll
    for (int u = 0; u < 4; ++u) ss[u] = csr_src[j + u];
#pragma unroll
    for (int u = 0; u < 4; ++u) hh[u] = bf2f(h16[(size_t)ss[u] * HID + d]);
#pragma unroll
    for (int u = 0; u < 4; ++u) ee[u] = csr_ea[j + u];
#pragma unroll
    for (int u = 0; u < 4; ++u) {
      P0 = fmaf(ee[u].x, hh[u], P0);
      P1 = fmaf(ee[u].y, hh[u], P1);
      P2 = fmaf(ee[u].z, hh[u], P2);
      P3 = fmaf(ee[u].w, hh[u], P3);
    }
  }
  for (; j < end; ++j) {
    int s0 = csr_src[j];
    float4 e0 = csr_ea[j];
    float h0 = bf2f(h16[(size_t)s0 * HID + d]);
    P0 = fmaf(e0.x, h0, P0);
    P1 = fmaf(e0.y, h0, P1);
    P2 = fmaf(e0.z, h0, P2);
    P3 = fmaf(e0.w, h0, P3);
  }
  float acc = P0 * Wl[d];
  acc = fmaf(P1, Wl[HID + d], acc);
  acc = fmaf(P2, Wl[2 * HID + d], acc);
  acc = fmaf(P3, Wl[3 * HID + d], acc);
  agg[(size_t)node * HID + d] = acc;
}

// hn = relu(agg@rel_w + rel_b + h@root_w) + h@res_w ; 8 nodes per wave.
// Also writes the bf16 shadow of hn for the next layer's gather.
__global__ __launch_bounds__(256, 8)
void node_kernel(const float* __restrict__ h,
                 const float* __restrict__ agg,
                 const float* __restrict__ rel_w,
                 const float* __restrict__ rel_b,
                 const float* __restrict__ root_w,
                 const float* __restrict__ res_w,
                 float* __restrict__ hn,
                 unsigned short* __restrict__ hn16, int n) {
  int wid = threadIdx.x >> 6;
  int d = threadIdx.x & 63;
  int base = (blockIdx.x * 4 + wid) * 8;
  if (base >= n) return;
  float bd = rel_b[d];
  float hval[8], aval[8], acc2[8], accR[8];
#pragma unroll
  for (int i = 0; i < 8; ++i) {
    int node = base + i;
    bool ok = node < n;
    hval[i] = ok ? h[(size_t)node * HID + d] : 0.f;
    aval[i] = ok ? agg[(size_t)node * HID + d] : 0.f;
    acc2[i] = bd;
    accR[i] = 0.f;
  }
#pragma unroll 8
  for (int k = 0; k < HID; ++k) {
    float wr = rel_w[k * HID + d];
    float wo = root_w[k * HID + d];
    float wq = res_w[k * HID + d];
#pragma unroll
    for (int i = 0; i < 8; ++i) {
      float hk = bcastf(hval[i], k);
      float ak = bcastf(aval[i], k);
      acc2[i] = fmaf(ak, wr, acc2[i]);
      acc2[i] = fmaf(hk, wo, acc2[i]);
      accR[i] = fmaf(hk, wq, accR[i]);
    }
  }
#pragma unroll
  for (int i = 0; i < 8; ++i) {
    int node = base + i;
    if (node < n) {
      float v = fmaxf(acc2[i], 0.f) + accR[i];
      hn[(size_t)node * HID + d] = v;
      hn16[(size_t)node * HID + d] = f2bf(v);
    }
  }
}

// ---- MFMA head ----
// out = gelu(h@w1 + b1)@w2 + b2 as [50000x64]@[64x512] MFMA GEMM + fused epilogue.
// Block = 16 nodes, 4 waves; wave w owns ff columns [w*128, w*128+128) (8 n-tiles).
// Split-bf16 for fp32-level accuracy: w1 = hi + lo (prep kernel); A = h split
// in-register vs fp32 h. acc = a_hi*b_hi + a_hi*b_lo + a_lo*b_hi (drop lo*lo).
// Fragment layouts (m89-verified): A row=lane&15, k=(lane>>4)*8+j;
// B col=lane&15, same k; C/D col=lane&15, row=(lane>>4)*4+reg.
__global__ __launch_bounds__(256, 4)
void head_kernel(const float* __restrict__ h,
                 const unsigned short* __restrict__ h16,
                 const unsigned short* __restrict__ w1bhi,
                 const unsigned short* __restrict__ w1blo,
                 const float* __restrict__ b1,
                 const float* __restrict__ w2,
                 const float* __restrict__ b2,
                 float* __restrict__ out, int n) {
  __shared__ float red[4][16];
  int tid = threadIdx.x;
  int w = tid >> 6;
  int l = tid & 63;
  int row = l & 15;
  int g = l >> 4;
  int base = blockIdx.x * 16;
  int node = base + row;
  if (node >= n) node = n - 1;   // duplicate last row; writes are guarded
  f32x4 acc[8];
#pragma unroll
  for (int t = 0; t < 8; ++t) acc[t] = (f32x4){0.f, 0.f, 0.f, 0.f};
#pragma unroll
  for (int kt = 0; kt < 2; ++kt) {
    int koff = kt * 32 + g * 8;
    bf16x8 ahi = *(const bf16x8*)(h16 + (size_t)node * HID + koff);
    const float* hp = h + (size_t)node * HID + koff;
    bf16x8 alo;
#pragma unroll
    for (int j = 0; j < 8; ++j) {
      float r = hp[j] - bf2f((unsigned short)ahi[j]);
      alo[j] = (short)f2bf(r);
    }
#pragma unroll
    for (int t = 0; t < 8; ++t) {
      int f = kt * 32 + w * 8 + t;
      bf16x8 bhi = *(const bf16x8*)(w1bhi + (size_t)f * 512 + l * 8);
      bf16x8 blo = *(const bf16x8*)(w1blo + (size_t)f * 512 + l * 8);
      acc[t] = __builtin_amdgcn_mfma_f32_16x16x32_bf16(alo, bhi, acc[t], 0, 0, 0);
      acc[t] = __builtin_amdgcn_mfma_f32_16x16x32_bf16(ahi, blo, acc[t], 0, 0, 0);
      acc[t] = __builtin_amdgcn_mfma_f32_16x16x32_bf16(ahi, bhi, acc[t], 0, 0, 0);
    }
  }
  // epilogue: bias + exact GELU + w2 dot, reduce over ff
  float s0 = 0.f, s1 = 0.f, s2 = 0.f, s3 = 0.f;
#pragma unroll
  for (int t = 0; t < 8; ++t) {
    int ff = (w * 8 + t) * 16 + row;   // C col = lane&15
    float bb = b1[ff];
    float ww = w2[ff];
    float xv, gl;
    xv = acc[t][0] + bb; gl = 0.5f * xv * (1.f + erff(xv * 0.70710678118654752f)); s0 = fmaf(gl, ww, s0);
    xv = acc[t][1] + bb; gl = 0.5f * xv * (1.f + erff(xv * 0.70710678118654752f)); s1 = fmaf(gl, ww, s1);
    xv = acc[t][2] + bb; gl = 0.5f * xv * (1.f + erff(xv * 0.70710678118654752f)); s2 = fmaf(gl, ww, s2);
    xv = acc[t][3] + bb; gl = 0.5f * xv * (1.f + erff(xv * 0.70710678118654752f)); s3 = fmaf(gl, ww, s3);
  }
#pragma unroll
  for (int off = 1; off < 16; off <<= 1) {
    s0 += __shfl_xor(s0, off);
    s1 += __shfl_xor(s1, off);
    s2 += __shfl_xor(s2, off);
    s3 += __shfl_xor(s3, off);
  }
  if ((l & 15) == 0) {
    red[w][g * 4 + 0] = s0;
    red[w][g * 4 + 1] = s1;
    red[w][g * 4 + 2] = s2;
    red[w][g * 4 + 3] = s3;
  }
  __syncthreads();
  if (tid < 16 && base + tid < n)
    out[base + tid] = red[0][tid] + red[1][tid] + red[2][tid] + red[3][tid] + b2[0];
}

extern "C" void kernel_launch(void* const* d_in, const int* in_sizes, int n_in,
                              void* d_out, int out_size, void* d_ws, size_t ws_size,
                              hipStream_t stream) {
  const int*   x          = (const int*)d_in[0];
  const int*   edge_index = (const int*)d_in[1];
  const float* edge_attr  = (const float*)d_in[2];
  const float* vert_emb   = (const float*)d_in[3];
  const float* edge_emb_w = (const float*)d_in[4];
  const float* edge_lin_w = (const float*)d_in[5];
  const float* rel_w      = (const float*)d_in[6];
  const float* rel_b      = (const float*)d_in[7];
  const float* root_w     = (const float*)d_in[8];
  const float* res_w      = (const float*)d_in[9];
  const float* w1         = (const float*)d_in[10];
  const float* b1         = (const float*)d_in[11];
  const float* w2         = (const float*)d_in[12];
  const float* b2         = (const float*)d_in[13];

  const int n = in_sizes[0];
  const int E = in_sizes[2] / 4;
  const int* src = edge_index;
  const int* dst = edge_index + E;
  const int nb = (n + 255) / 256;   // scan blocks (196 for n=50000)

  // workspace layout:
  //   Wl[2048] f | hA[n*64] f | hB[n*64] f | agg[n*64] f | csr_ea[E] float4 |
  //   csr_src[E] int | row_ptr[n+1] int | cursor[n] int | deg[n] int |
  //   bsum[256] int | boff[256] int | w1bhi[32768] u16 | w1blo[32768] u16 |
  //   h16A[n*64] u16 | h16B[n*64] u16
  float* ws   = (float*)d_ws;
  float* Wl   = ws;
  float* hA   = ws + 2048;
  float* hB   = hA + (size_t)n * HID;
  float* agg  = hB + (size_t)n * HID;
  float4* csr_ea = (float4*)(agg + (size_t)n * HID);
  int* csr_src = (int*)(csr_ea + (size_t)E);
  int* row_ptr = csr_src + E;
  int* cursor  = row_ptr + (n + 1);
  int* deg     = cursor + n;
  int* bsum    = deg + n;
  int* boff    = bsum + 256;
  unsigned short* w1bhi = (unsigned short*)(boff + 256);
  unsigned short* w1blo = w1bhi + 64 * 512;
  unsigned short* h16A  = w1blo + 64 * 512;
  unsigned short* h16B  = h16A + (size_t)n * HID;

  prep_wl_kernel<<<dim3(NLAY), dim3(256), 0, stream>>>(edge_emb_w, edge_lin_w, Wl);
  prep_w1b_kernel<<<dim3(16), dim3(256), 0, stream>>>(w1, w1bhi, w1blo);

  int totalHD = n * HID;
  embed_kernel<<<dim3((totalHD + 255) / 256), dim3(256), 0, stream>>>(
      x, vert_emb, hA, h16A, n);

  // CSR build (amortized over 5 layers)
  zero_deg_kernel<<<dim3((n + 255) / 256), dim3(256), 0, stream>>>(deg, n);
  hist_kernel<<<dim3((E + 255) / 256), dim3(256), 0, stream>>>(dst, deg, E);
  bsum_kernel<<<dim3(nb), dim3(256), 0, stream>>>(deg, bsum, n);
  bscan_kernel<<<dim3(1), dim3(256), 0, stream>>>(bsum, boff, nb);
  scan3_kernel<<<dim3(nb), dim3(256), 0, stream>>>(deg, boff, row_ptr, cursor, n);
  scatter_kernel<<<dim3((E + 255) / 256), dim3(256), 0, stream>>>(
      src, dst, (const float4*)edge_attr, cursor, csr_src, csr_ea, E);

  float* hc = hA;
  float* hx = hB;
  unsigned short* h16c = h16A;
  unsigned short* h16x = h16B;
  for (int l = 0; l < NLAY; ++l) {
    gather_kernel<<<dim3((n + 3) / 4), dim3(256), 0, stream>>>(
        row_ptr, csr_src, csr_ea, Wl + l * 4 * HID, h16c, agg, n);
    node_kernel<<<dim3((n + 31) / 32), dim3(256), 0, stream>>>(
        hc, agg, rel_w + l * HID * HID, rel_b + l * HID,
        root_w + l * HID * HID, res_w + l * HID * HID, hx, h16x, n);
    float* t = hc; hc = hx; hx = t;
    unsigned short* t16 = h16c; h16c = h16x; h16x = t16;
  }

  head_kernel<<<dim3((n + 15) / 16), dim3(256), 0, stream>>>(
      hc, h16c, w1bhi, w1blo, b1, w2, b2, (float*)d_out, n);
}

// Round 13
// 453.697 us; speedup vs baseline: 1.3022x; 1.1804x over previous
//
#include <hip/hip_runtime.h>
#include <math.h>

#define HID 64
#define NLAY 5
#define NFF 512

typedef __attribute__((ext_vector_type(8))) short bf16x8;
typedef __attribute__((ext_vector_type(4))) float f32x4;

// fp32 -> bf16 (round-to-nearest-even), bit trick; and back.
__device__ __forceinline__ unsigned short f2bf(float x) {
  unsigned int b = __float_as_uint(x);
  b += 0x7FFFu + ((b >> 16) & 1u);
  return (unsigned short)(b >> 16);
}
__device__ __forceinline__ float bf2f(unsigned short u) {
  return __uint_as_float((unsigned int)u << 16);
}

// Wl[l] = edge_emb_w (4x64) @ edge_lin_w[l] (64x64)  -> [4][64] per layer
__global__ void prep_wl_kernel(const float* __restrict__ edge_emb_w,
                               const float* __restrict__ edge_lin_w,
                               float* __restrict__ Wl) {
  int l = blockIdx.x;
  int t = threadIdx.x;
  int j = t >> 6;
  int d = t & 63;
  const float* ew = edge_emb_w + j * HID;
  const float* lw = edge_lin_w + l * HID * HID;
  float acc = 0.f;
#pragma unroll
  for (int k = 0; k < HID; ++k) acc = fmaf(ew[k], lw[k * HID + d], acc);
  Wl[(l * 4 + j) * HID + d] = acc;
}

// Split w1 into bf16 hi/lo MFMA B-fragments (one-time).
// Frag f = kt*32 + nt. Lane l holds B[kt*32+(l>>4)*8+j][nt*16+(l&15)], j=0..7.
__global__ void prep_w1b_kernel(const float* __restrict__ w1,
                                unsigned short* __restrict__ w1bhi,
                                unsigned short* __restrict__ w1blo) {
  int t = blockIdx.x * 256 + threadIdx.x;   // 0..4095
  int f = t >> 6;
  int l = t & 63;
  int kt = f >> 5;
  int nt = f & 31;
  int krow = kt * 32 + (l >> 4) * 8;
  int col = nt * 16 + (l & 15);
#pragma unroll
  for (int j = 0; j < 8; ++j) {
    float v = w1[(size_t)(krow + j) * NFF + col];
    unsigned short hi = f2bf(v);
    unsigned short lo = f2bf(v - bf2f(hi));
    w1bhi[(size_t)t * 8 + j] = hi;
    w1blo[(size_t)t * 8 + j] = lo;
  }
}

// Split rel/root/res (5 layers x 3 mats of 64x64) into bf16 hi/lo B-fragments.
// mi = layer*3 + mat. Frag f = kt*4 + nt (kt of 32 k's, nt of 16 cols).
// Stored at nw*[ ((mi*8 + f)*64 + l)*8 + j ].
__global__ void prep_nw_kernel(const float* __restrict__ rel_w,
                               const float* __restrict__ root_w,
                               const float* __restrict__ res_w,
                               unsigned short* __restrict__ nwhi,
                               unsigned short* __restrict__ nwlo) {
  int mi = blockIdx.x;            // 0..14
  int layer = mi / 3, mat = mi % 3;
  const float* W = (mat == 0 ? rel_w : (mat == 1 ? root_w : res_w)) +
                   (size_t)layer * HID * HID;
  int t = threadIdx.x;            // 0..511
  int f = t >> 6, l = t & 63;
  int kt = f >> 2, nt = f & 3;
  int krow = kt * 32 + (l >> 4) * 8;
  int col = nt * 16 + (l & 15);
#pragma unroll
  for (int j = 0; j < 8; ++j) {
    float v = W[(size_t)(krow + j) * HID + col];
    unsigned short hi = f2bf(v);
    unsigned short lo = f2bf(v - bf2f(hi));
    size_t off = (((size_t)mi * 8 + f) * 64 + l) * 8 + j;
    nwhi[off] = hi;
    nwlo[off] = lo;
  }
}

// h[n][d] = vert_emb[x[n]][d] ; also bf16 shadow for the gather path.
__global__ void embed_kernel(const int* __restrict__ x,
                             const float* __restrict__ vert_emb,
                             float* __restrict__ h,
                             unsigned short* __restrict__ h16, int n) {
  int idx = blockIdx.x * blockDim.x + threadIdx.x;
  if (idx >= n * HID) return;
  int node = idx >> 6;
  int d = idx & 63;
  float v = vert_emb[x[node] * HID + d];
  h[idx] = v;
  h16[idx] = f2bf(v);
}

// ---- CSR build (once per call, reused across 5 layers) ----

__global__ void zero_deg_kernel(int* __restrict__ deg, int n) {
  int i = blockIdx.x * blockDim.x + threadIdx.x;
  if (i < n) deg[i] = 0;
}

__global__ void hist_kernel(const int* __restrict__ dst, int* __restrict__ deg, int E) {
  int e = blockIdx.x * blockDim.x + threadIdx.x;
  if (e < E) atomicAdd(&deg[dst[e]], 1);
}

__global__ void bsum_kernel(const int* __restrict__ deg, int* __restrict__ bsum, int n) {
  __shared__ int s[256];
  int t = threadIdx.x;
  int i = blockIdx.x * 256 + t;
  s[t] = (i < n) ? deg[i] : 0;
  __syncthreads();
#pragma unroll
  for (int off = 128; off > 0; off >>= 1) {
    if (t < off) s[t] += s[t + off];
    __syncthreads();
  }
  if (t == 0) bsum[blockIdx.x] = s[0];
}

__global__ void bscan_kernel(const int* __restrict__ bsum, int* __restrict__ boff, int nb) {
  __shared__ int s[256];
  int t = threadIdx.x;
  int v = (t < nb) ? bsum[t] : 0;
  s[t] = v;
  __syncthreads();
#pragma unroll
  for (int off = 1; off < 256; off <<= 1) {
    int u = (t >= off) ? s[t - off] : 0;
    __syncthreads();
    s[t] += u;
    __syncthreads();
  }
  if (t < nb) boff[t] = s[t] - v;   // exclusive
}

__global__ void scan3_kernel(const int* __restrict__ deg, const int* __restrict__ boff,
                             int* __restrict__ row_ptr, int* __restrict__ cursor, int n) {
  __shared__ int s[256];
  int t = threadIdx.x;
  int i = blockIdx.x * 256 + t;
  int v = (i < n) ? deg[i] : 0;
  s[t] = v;
  __syncthreads();
#pragma unroll
  for (int off = 1; off < 256; off <<= 1) {
    int u = (t >= off) ? s[t - off] : 0;
    __syncthreads();
    s[t] += u;
    __syncthreads();
  }
  if (i < n) {
    int excl = boff[blockIdx.x] + s[t] - v;
    row_ptr[i] = excl;
    cursor[i] = excl;
    if (i == n - 1) row_ptr[n] = excl + v;
  }
}

// Packed 32B record per edge at csr2[2*pos], csr2[2*pos+1]:
//   [0] = ea (float4), [1].x = src (as int bits).
// One 64B line dirtied per edge (was two: separate csr_src + csr_ea arrays ->
// WRITE_SIZE 78 MB for 16 MB payload). Record 32B-aligned -> both stores same line.
__global__ void scatter_kernel(const int* __restrict__ src,
                               const int* __restrict__ dst,
                               const float4* __restrict__ edge_attr,
                               int* __restrict__ cursor,
                               float4* __restrict__ csr2, int E) {
  int e = blockIdx.x * blockDim.x + threadIdx.x;
  if (e >= E) return;
  int pos = atomicAdd(&cursor[dst[e]], 1);
  csr2[(size_t)2 * pos] = edge_attr[e];
  float4 m;
  m.x = __int_as_float(src[e]);
  m.y = 0.f; m.z = 0.f; m.w = 0.f;
  csr2[(size_t)2 * pos + 1] = m;
}

// ---- gather: 1 wave per dst node, lane = dim, bf16 h payload ----
// Rank-4 form: P_r[d] = sum_j ea_j[r]*h[src_j][d]; agg = sum_r Wl[r][d]*P_r[d].
__global__ __launch_bounds__(256, 8)
void gather_kernel(const int* __restrict__ row_ptr,
                   const float4* __restrict__ csr2,
                   const float* __restrict__ Wl,   // [4][64]
                   const unsigned short* __restrict__ h16,
                   float* __restrict__ agg, int n) {
  int wid = threadIdx.x >> 6;
  int d = threadIdx.x & 63;
  int node = blockIdx.x * 4 + wid;
  if (node >= n) return;
  int beg = __builtin_amdgcn_readfirstlane(row_ptr[node]);
  int end = __builtin_amdgcn_readfirstlane(row_ptr[node + 1]);
  const int* csri = (const int*)csr2;
  float P0 = 0.f, P1 = 0.f, P2 = 0.f, P3 = 0.f;
  int j = beg;
  for (; j + 16 <= end; j += 16) {
    int ss[16];
    float hh[16];
    float4 ee[16];
#pragma unroll
    for (int u = 0; u < 16; ++u) ss[u] = csri[((size_t)2 * (j + u) + 1) * 4];
#pragma unroll
    for (int u = 0; u < 16; ++u) hh[u] = bf2f(h16[(size_t)ss[u] * HID + d]);
#pragma unroll
    for (int u = 0; u < 16; ++u) ee[u] = csr2[(size_t)2 * (j + u)];
#pragma unroll
    for (int u = 0; u < 16; ++u) {
      P0 = fmaf(ee[u].x, hh[u], P0);
      P1 = fmaf(ee[u].y, hh[u], P1);
      P2 = fmaf(ee[u].z, hh[u], P2);
      P3 = fmaf(ee[u].w, hh[u], P3);
    }
  }
  for (; j + 4 <= end; j += 4) {
    int ss[4];
    float hh[4];
    float4 ee[4];
#pragma unroll
    for (int u = 0; u < 4; ++u) ss[u] = csri[((size_t)2 * (j + u) + 1) * 4];
#pragma unroll
    for (int u = 0; u < 4; ++u) hh[u] = bf2f(h16[(size_t)ss[u] * HID + d]);
#pragma unroll
    for (int u = 0; u < 4; ++u) ee[u] = csr2[(size_t)2 * (j + u)];
#pragma unroll
    for (int u = 0; u < 4; ++u) {
      P0 = fmaf(ee[u].x, hh[u], P0);
      P1 = fmaf(ee[u].y, hh[u], P1);
      P2 = fmaf(ee[u].z, hh[u], P2);
      P3 = fmaf(ee[u].w, hh[u], P3);
    }
  }
  for (; j < end; ++j) {
    int s0 = csri[((size_t)2 * j + 1) * 4];
    float4 e0 = csr2[(size_t)2 * j];
    float h0 = bf2f(h16[(size_t)s0 * HID + d]);
    P0 = fmaf(e0.x, h0, P0);
    P1 = fmaf(e0.y, h0, P1);
    P2 = fmaf(e0.z, h0, P2);
    P3 = fmaf(e0.w, h0, P3);
  }
  float acc = P0 * Wl[d];
  acc = fmaf(P1, Wl[HID + d], acc);
  acc = fmaf(P2, Wl[2 * HID + d], acc);
  acc = fmaf(P3, Wl[3 * HID + d], acc);
  agg[(size_t)node * HID + d] = acc;
}

// ---- MFMA node layer: hn = relu(agg@rel + b + h@root) + h@res ----
// Block = 16 nodes, 4 waves; wave w owns output cols [w*16, w*16+16).
// Split-bf16 (validated in head, r12): acc = a_lo*b_hi + a_hi*b_lo + a_hi*b_hi.
// Layouts (m89-verified): A row=lane&15 (node), k=(lane>>4)*8+j;
// B col=lane&15; C/D col=lane&15 (out dim), row=(lane>>4)*4+reg (node).
__global__ __launch_bounds__(256, 4)
void node_mfma_kernel(const float* __restrict__ h,
                      const unsigned short* __restrict__ h16,
                      const float* __restrict__ agg,
                      const unsigned short* __restrict__ nwhi,  // this layer's 3 mats
                      const unsigned short* __restrict__ nwlo,
                      const float* __restrict__ rel_b,
                      float* __restrict__ hn,
                      unsigned short* __restrict__ hn16, int n) {
  int tid = threadIdx.x;
  int w = tid >> 6;
  int l = tid & 63;
  int q = l & 15;     // A node-row / C col-in-tile
  int g = l >> 4;
  int base = blockIdx.x * 16;
  int node = base + q;
  if (node >= n) node = n - 1;   // clamp; stores guarded
  bf16x8 aghi[2], aglo[2], ahhi[2], ahlo[2];
#pragma unroll
  for (int kt = 0; kt < 2; ++kt) {
    int koff = kt * 32 + g * 8;
    const float* ap = agg + (size_t)node * HID + koff;
    const float* hp = h + (size_t)node * HID + koff;
    ahhi[kt] = *(const bf16x8*)(h16 + (size_t)node * HID + koff);
#pragma unroll
    for (int j = 0; j < 8; ++j) {
      float av = ap[j];
      unsigned short hi = f2bf(av);
      aghi[kt][j] = (short)hi;
      aglo[kt][j] = (short)f2bf(av - bf2f(hi));
      float r = hp[j] - bf2f((unsigned short)ahhi[kt][j]);
      ahlo[kt][j] = (short)f2bf(r);
    }
  }
  f32x4 aR = {0.f, 0.f, 0.f, 0.f};
  f32x4 aO = {0.f, 0.f, 0.f, 0.f};
  f32x4 aS = {0.f, 0.f, 0.f, 0.f};
#pragma unroll
  for (int kt = 0; kt < 2; ++kt) {
    int f = kt * 4 + w;
    const bf16x8* bRh = (const bf16x8*)(nwhi + (((size_t)0 * 8 + f) * 64 + l) * 8);
    const bf16x8* bRl = (const bf16x8*)(nwlo + (((size_t)0 * 8 + f) * 64 + l) * 8);
    const bf16x8* bOh = (const bf16x8*)(nwhi + (((size_t)1 * 8 + f) * 64 + l) * 8);
    const bf16x8* bOl = (const bf16x8*)(nwlo + (((size_t)1 * 8 + f) * 64 + l) * 8);
    const bf16x8* bSh = (const bf16x8*)(nwhi + (((size_t)2 * 8 + f) * 64 + l) * 8);
    const bf16x8* bSl = (const bf16x8*)(nwlo + (((size_t)2 * 8 + f) * 64 + l) * 8);
    aR = __builtin_amdgcn_mfma_f32_16x16x32_bf16(aglo[kt], *bRh, aR, 0, 0, 0);
    aR = __builtin_amdgcn_mfma_f32_16x16x32_bf16(aghi[kt], *bRl, aR, 0, 0, 0);
    aR = __builtin_amdgcn_mfma_f32_16x16x32_bf16(aghi[kt], *bRh, aR, 0, 0, 0);
    aO = __builtin_amdgcn_mfma_f32_16x16x32_bf16(ahlo[kt], *bOh, aO, 0, 0, 0);
    aO = __builtin_amdgcn_mfma_f32_16x16x32_bf16(ahhi[kt], *bOl, aO, 0, 0, 0);
    aO = __builtin_amdgcn_mfma_f32_16x16x32_bf16(ahhi[kt], *bOh, aO, 0, 0, 0);
    aS = __builtin_amdgcn_mfma_f32_16x16x32_bf16(ahlo[kt], *bSh, aS, 0, 0, 0);
    aS = __builtin_amdgcn_mfma_f32_16x16x32_bf16(ahhi[kt], *bSl, aS, 0, 0, 0);
    aS = __builtin_amdgcn_mfma_f32_16x16x32_bf16(ahhi[kt], *bSh, aS, 0, 0, 0);
  }
  int col = w * 16 + q;
  float bd = rel_b[col];
#pragma unroll
  for (int r = 0; r < 4; ++r) {
    int nd = base + g * 4 + r;
    if (nd < n) {
      float v = fmaxf(aR[r] + aO[r] + bd, 0.f) + aS[r];
      hn[(size_t)nd * HID + col] = v;
      hn16[(size_t)nd * HID + col] = f2bf(v);
    }
  }
}

// ---- MFMA head (r12-validated) ----
__global__ __launch_bounds__(256, 4)
void head_kernel(const float* __restrict__ h,
                 const unsigned short* __restrict__ h16,
                 const unsigned short* __restrict__ w1bhi,
                 const unsigned short* __restrict__ w1blo,
                 const float* __restrict__ b1,
                 const float* __restrict__ w2,
                 const float* __restrict__ b2,
                 float* __restrict__ out, int n) {
  __shared__ float red[4][16];
  int tid = threadIdx.x;
  int w = tid >> 6;
  int l = tid & 63;
  int row = l & 15;
  int g = l >> 4;
  int base = blockIdx.x * 16;
  int node = base + row;
  if (node >= n) node = n - 1;
  f32x4 acc[8];
#pragma unroll
  for (int t = 0; t < 8; ++t) acc[t] = (f32x4){0.f, 0.f, 0.f, 0.f};
#pragma unroll
  for (int kt = 0; kt < 2; ++kt) {
    int koff = kt * 32 + g * 8;
    bf16x8 ahi = *(const bf16x8*)(h16 + (size_t)node * HID + koff);
    const float* hp = h + (size_t)node * HID + koff;
    bf16x8 alo;
#pragma unroll
    for (int j = 0; j < 8; ++j) {
      float r = hp[j] - bf2f((unsigned short)ahi[j]);
      alo[j] = (short)f2bf(r);
    }
#pragma unroll
    for (int t = 0; t < 8; ++t) {
      int f = kt * 32 + w * 8 + t;
      bf16x8 bhi = *(const bf16x8*)(w1bhi + (size_t)f * 512 + l * 8);
      bf16x8 blo = *(const bf16x8*)(w1blo + (size_t)f * 512 + l * 8);
      acc[t] = __builtin_amdgcn_mfma_f32_16x16x32_bf16(alo, bhi, acc[t], 0, 0, 0);
      acc[t] = __builtin_amdgcn_mfma_f32_16x16x32_bf16(ahi, blo, acc[t], 0, 0, 0);
      acc[t] = __builtin_amdgcn_mfma_f32_16x16x32_bf16(ahi, bhi, acc[t], 0, 0, 0);
    }
  }
  float s0 = 0.f, s1 = 0.f, s2 = 0.f, s3 = 0.f;
#pragma unroll
  for (int t = 0; t < 8; ++t) {
    int ff = (w * 8 + t) * 16 + row;
    float bb = b1[ff];
    float ww = w2[ff];
    float xv, gl;
    xv = acc[t][0] + bb; gl = 0.5f * xv * (1.f + erff(xv * 0.70710678118654752f)); s0 = fmaf(gl, ww, s0);
    xv = acc[t][1] + bb; gl = 0.5f * xv * (1.f + erff(xv * 0.70710678118654752f)); s1 = fmaf(gl, ww, s1);
    xv = acc[t][2] + bb; gl = 0.5f * xv * (1.f + erff(xv * 0.70710678118654752f)); s2 = fmaf(gl, ww, s2);
    xv = acc[t][3] + bb; gl = 0.5f * xv * (1.f + erff(xv * 0.70710678118654752f)); s3 = fmaf(gl, ww, s3);
  }
#pragma unroll
  for (int off = 1; off < 16; off <<= 1) {
    s0 += __shfl_xor(s0, off);
    s1 += __shfl_xor(s1, off);
    s2 += __shfl_xor(s2, off);
    s3 += __shfl_xor(s3, off);
  }
  if ((l & 15) == 0) {
    red[w][g * 4 + 0] = s0;
    red[w][g * 4 + 1] = s1;
    red[w][g * 4 + 2] = s2;
    red[w][g * 4 + 3] = s3;
  }
  __syncthreads();
  if (tid < 16 && base + tid < n)
    out[base + tid] = red[0][tid] + red[1][tid] + red[2][tid] + red[3][tid] + b2[0];
}

extern "C" void kernel_launch(void* const* d_in, const int* in_sizes, int n_in,
                              void* d_out, int out_size, void* d_ws, size_t ws_size,
                              hipStream_t stream) {
  const int*   x          = (const int*)d_in[0];
  const int*   edge_index = (const int*)d_in[1];
  const float* edge_attr  = (const float*)d_in[2];
  const float* vert_emb   = (const float*)d_in[3];
  const float* edge_emb_w = (const float*)d_in[4];
  const float* edge_lin_w = (const float*)d_in[5];
  const float* rel_w      = (const float*)d_in[6];
  const float* rel_b      = (const float*)d_in[7];
  const float* root_w     = (const float*)d_in[8];
  const float* res_w      = (const float*)d_in[9];
  const float* w1         = (const float*)d_in[10];
  const float* b1         = (const float*)d_in[11];
  const float* w2         = (const float*)d_in[12];
  const float* b2         = (const float*)d_in[13];

  const int n = in_sizes[0];
  const int E = in_sizes[2] / 4;
  const int* src = edge_index;
  const int* dst = edge_index + E;
  const int nb = (n + 255) / 256;

  // workspace layout:
  //   Wl[2048] f | hA[n*64] f | hB[n*64] f | agg[n*64] f | csr2[2E] float4 |
  //   row_ptr[n+1] | cursor[n] | deg[n] | bsum[256] | boff[256] (ints) |
  //   (16B-align) w1bhi[32768] | w1blo[32768] | nwhi[61440] | nwlo[61440] |
  //   h16A[n*64] | h16B[n*64] (u16)
  float* ws   = (float*)d_ws;
  float* Wl   = ws;
  float* hA   = ws + 2048;
  float* hB   = hA + (size_t)n * HID;
  float* agg  = hB + (size_t)n * HID;
  float4* csr2 = (float4*)(agg + (size_t)n * HID);
  int* row_ptr = (int*)(csr2 + (size_t)2 * E);
  int* cursor  = row_ptr + (n + 1);
  int* deg     = cursor + n;
  int* bsum    = deg + n;
  int* boff    = bsum + 256;
  unsigned short* w1bhi = (unsigned short*)(((size_t)(boff + 256) + 15) & ~(size_t)15);
  unsigned short* w1blo = w1bhi + 64 * 512;
  unsigned short* nwhi  = w1blo + 64 * 512;
  unsigned short* nwlo  = nwhi + NLAY * 3 * 4096;
  unsigned short* h16A  = nwlo + NLAY * 3 * 4096;
  unsigned short* h16B  = h16A + (size_t)n * HID;

  prep_wl_kernel<<<dim3(NLAY), dim3(256), 0, stream>>>(edge_emb_w, edge_lin_w, Wl);
  prep_w1b_kernel<<<dim3(16), dim3(256), 0, stream>>>(w1, w1bhi, w1blo);
  prep_nw_kernel<<<dim3(NLAY * 3), dim3(512), 0, stream>>>(rel_w, root_w, res_w, nwhi, nwlo);

  int totalHD = n * HID;
  embed_kernel<<<dim3((totalHD + 255) / 256), dim3(256), 0, stream>>>(
      x, vert_emb, hA, h16A, n);

  // CSR build (amortized over 5 layers)
  zero_deg_kernel<<<dim3((n + 255) / 256), dim3(256), 0, stream>>>(deg, n);
  hist_kernel<<<dim3((E + 255) / 256), dim3(256), 0, stream>>>(dst, deg, E);
  bsum_kernel<<<dim3(nb), dim3(256), 0, stream>>>(deg, bsum, n);
  bscan_kernel<<<dim3(1), dim3(256), 0, stream>>>(bsum, boff, nb);
  scan3_kernel<<<dim3(nb), dim3(256), 0, stream>>>(deg, boff, row_ptr, cursor, n);
  scatter_kernel<<<dim3((E + 255) / 256), dim3(256), 0, stream>>>(
      src, dst, (const float4*)edge_attr, cursor, csr2, E);

  float* hc = hA;
  float* hx = hB;
  unsigned short* h16c = h16A;
  unsigned short* h16x = h16B;
  for (int l = 0; l < NLAY; ++l) {
    gather_kernel<<<dim3((n + 3) / 4), dim3(256), 0, stream>>>(
        row_ptr, csr2, Wl + l * 4 * HID, h16c, agg, n);
    node_mfma_kernel<<<dim3((n + 15) / 16), dim3(256), 0, stream>>>(
        hc, h16c, agg, nwhi + (size_t)l * 3 * 4096, nwlo + (size_t)l * 3 * 4096,
        rel_b + l * HID, hx, h16x, n);
    float* t = hc; hc = hx; hx = t;
    unsigned short* t16 = h16c; h16c = h16x; h16x = t16;
  }

  head_kernel<<<dim3((n + 15) / 16), dim3(256), 0, stream>>>(
      hc, h16c, w1bhi, w1blo, b1, w2, b2, (float*)d_out, n);
}

// Round 14
// 451.303 us; speedup vs baseline: 1.3091x; 1.0053x over previous
//
#include <hip/hip_runtime.h>
#include <math.h>

#define HID 64
#define NLAY 5
#define NFF 512

typedef __attribute__((ext_vector_type(8))) short bf16x8;
typedef __attribute__((ext_vector_type(4))) float f32x4;

// fp32 -> bf16 (round-to-nearest-even), bit trick; and back.
__device__ __forceinline__ unsigned short f2bf(float x) {
  unsigned int b = __float_as_uint(x);
  b += 0x7FFFu + ((b >> 16) & 1u);
  return (unsigned short)(b >> 16);
}
__device__ __forceinline__ float bf2f(unsigned short u) {
  return __uint_as_float((unsigned int)u << 16);
}

// One fused prep dispatch (saves 2 launches):
//  blocks 0..4   : Wl[l] = edge_emb_w @ edge_lin_w[l]          (prep_wl)
//  blocks 5..20  : split w1 into bf16 hi/lo MFMA B-fragments    (prep_w1b)
//  blocks 21..35 : split rel/root/res into bf16 hi/lo fragments (prep_nw)
__global__ void prep_all_kernel(const float* __restrict__ edge_emb_w,
                                const float* __restrict__ edge_lin_w,
                                const float* __restrict__ w1,
                                const float* __restrict__ rel_w,
                                const float* __restrict__ root_w,
                                const float* __restrict__ res_w,
                                float* __restrict__ Wl,
                                unsigned short* __restrict__ w1bhi,
                                unsigned short* __restrict__ w1blo,
                                unsigned short* __restrict__ nwhi,
                                unsigned short* __restrict__ nwlo) {
  int bid = blockIdx.x;
  int tid = threadIdx.x;
  if (bid < 5) {
    int j = tid >> 6;
    int d = tid & 63;
    const float* ew = edge_emb_w + j * HID;
    const float* lw = edge_lin_w + bid * HID * HID;
    float acc = 0.f;
#pragma unroll
    for (int k = 0; k < HID; ++k) acc = fmaf(ew[k], lw[k * HID + d], acc);
    Wl[(bid * 4 + j) * HID + d] = acc;
  } else if (bid < 21) {
    int t = (bid - 5) * 256 + tid;   // 0..4095
    int f = t >> 6;
    int l = t & 63;
    int kt = f >> 5;
    int nt = f & 31;
    int krow = kt * 32 + (l >> 4) * 8;
    int col = nt * 16 + (l & 15);
#pragma unroll
    for (int j = 0; j < 8; ++j) {
      float v = w1[(size_t)(krow + j) * NFF + col];
      unsigned short hi = f2bf(v);
      unsigned short lo = f2bf(v - bf2f(hi));
      w1bhi[(size_t)t * 8 + j] = hi;
      w1blo[(size_t)t * 8 + j] = lo;
    }
  } else {
    int mi = bid - 21;               // 0..14 = layer*3 + mat
    int layer = mi / 3, mat = mi % 3;
    const float* W = (mat == 0 ? rel_w : (mat == 1 ? root_w : res_w)) +
                     (size_t)layer * HID * HID;
#pragma unroll
    for (int half = 0; half < 2; ++half) {
      int t = half * 256 + tid;      // 0..511
      int f = t >> 6, l = t & 63;
      int kt = f >> 2, nt = f & 3;
      int krow = kt * 32 + (l >> 4) * 8;
      int col = nt * 16 + (l & 15);
#pragma unroll
      for (int j = 0; j < 8; ++j) {
        float v = W[(size_t)(krow + j) * HID + col];
        unsigned short hi = f2bf(v);
        unsigned short lo = f2bf(v - bf2f(hi));
        size_t off = (((size_t)mi * 8 + f) * 64 + l) * 8 + j;
        nwhi[off] = hi;
        nwlo[off] = lo;
      }
    }
  }
}

// h[n][d] = vert_emb[x[n]][d]; bf16 shadow; also zeroes deg (fused zero_deg).
__global__ void embed_kernel(const int* __restrict__ x,
                             const float* __restrict__ vert_emb,
                             float* __restrict__ h,
                             unsigned short* __restrict__ h16,
                             int* __restrict__ deg, int n) {
  int idx = blockIdx.x * blockDim.x + threadIdx.x;
  if (idx >= n * HID) return;
  int node = idx >> 6;
  int d = idx & 63;
  float v = vert_emb[x[node] * HID + d];
  h[idx] = v;
  h16[idx] = f2bf(v);
  if (d == 0) deg[node] = 0;
}

// ---- CSR build ----

__global__ void hist_kernel(const int* __restrict__ dst, int* __restrict__ deg, int E) {
  int e = blockIdx.x * blockDim.x + threadIdx.x;
  if (e < E) atomicAdd(&deg[dst[e]], 1);
}

__global__ void bsum_kernel(const int* __restrict__ deg, int* __restrict__ bsum, int n) {
  __shared__ int s[256];
  int t = threadIdx.x;
  int i = blockIdx.x * 256 + t;
  s[t] = (i < n) ? deg[i] : 0;
  __syncthreads();
#pragma unroll
  for (int off = 128; off > 0; off >>= 1) {
    if (t < off) s[t] += s[t + off];
    __syncthreads();
  }
  if (t == 0) bsum[blockIdx.x] = s[0];
}

__global__ void bscan_kernel(const int* __restrict__ bsum, int* __restrict__ boff, int nb) {
  __shared__ int s[256];
  int t = threadIdx.x;
  int v = (t < nb) ? bsum[t] : 0;
  s[t] = v;
  __syncthreads();
#pragma unroll
  for (int off = 1; off < 256; off <<= 1) {
    int u = (t >= off) ? s[t - off] : 0;
    __syncthreads();
    s[t] += u;
    __syncthreads();
  }
  if (t < nb) boff[t] = s[t] - v;   // exclusive
}

__global__ void scan3_kernel(const int* __restrict__ deg, const int* __restrict__ boff,
                             int* __restrict__ row_ptr, int* __restrict__ cursor, int n) {
  __shared__ int s[256];
  int t = threadIdx.x;
  int i = blockIdx.x * 256 + t;
  int v = (i < n) ? deg[i] : 0;
  s[t] = v;
  __syncthreads();
#pragma unroll
  for (int off = 1; off < 256; off <<= 1) {
    int u = (t >= off) ? s[t - off] : 0;
    __syncthreads();
    s[t] += u;
    __syncthreads();
  }
  if (i < n) {
    int excl = boff[blockIdx.x] + s[t] - v;
    row_ptr[i] = excl;
    cursor[i] = excl;
    if (i == n - 1) row_ptr[n] = excl + v;
  }
}

// Packed 32B record per edge: csr2[2*pos] = ea, csr2[2*pos+1].x = src bits.
__global__ void scatter_kernel(const int* __restrict__ src,
                               const int* __restrict__ dst,
                               const float4* __restrict__ edge_attr,
                               int* __restrict__ cursor,
                               float4* __restrict__ csr2, int E) {
  int e = blockIdx.x * blockDim.x + threadIdx.x;
  if (e >= E) return;
  int pos = atomicAdd(&cursor[dst[e]], 1);
  csr2[(size_t)2 * pos] = edge_attr[e];
  float4 m;
  m.x = __int_as_float(src[e]);
  m.y = 0.f; m.z = 0.f; m.w = 0.f;
  csr2[(size_t)2 * pos + 1] = m;
}

// ---- fused layer: gather (rank-4, bf16 payload) + MFMA node transform ----
// Block = 16 nodes, 4 waves. Phase A: wave w gathers nodes base+4w..+3 into
// LDS sagg[16][65] (stride 65: write d-pattern and read (q + 8g) pattern both
// <=2 lanes/bank = conflict-free). Phase B: r13-validated MFMA node transform,
// A_agg built from sagg, A_h from h16/h. Kills the agg global round-trip and
// 5 dispatches per call.
__global__ __launch_bounds__(256, 4)
void layer_fused_kernel(const int* __restrict__ row_ptr,
                        const float4* __restrict__ csr2,
                        const float* __restrict__ Wl,   // this layer's [4][64]
                        const float* __restrict__ h,
                        const unsigned short* __restrict__ h16,
                        const unsigned short* __restrict__ nwhi,  // this layer
                        const unsigned short* __restrict__ nwlo,
                        const float* __restrict__ rel_b,          // this layer
                        float* __restrict__ hn,
                        unsigned short* __restrict__ hn16, int n) {
  __shared__ float sagg[16][65];
  int tid = threadIdx.x;
  int w = tid >> 6;
  int d = tid & 63;
  int base = blockIdx.x * 16;
  // ---- Phase A: gather ----
  float w0 = Wl[d], w1_ = Wl[HID + d], w2_ = Wl[2 * HID + d], w3_ = Wl[3 * HID + d];
  const int* csri = (const int*)csr2;
  for (int i = 0; i < 4; ++i) {
    int node = base + w * 4 + i;
    float P0 = 0.f, P1 = 0.f, P2 = 0.f, P3 = 0.f;
    if (node < n) {
      int beg = __builtin_amdgcn_readfirstlane(row_ptr[node]);
      int end = __builtin_amdgcn_readfirstlane(row_ptr[node + 1]);
      int j = beg;
      for (; j + 16 <= end; j += 16) {
        int ss[16];
        float hh[16];
        float4 ee[16];
#pragma unroll
        for (int u = 0; u < 16; ++u) ss[u] = csri[((size_t)2 * (j + u) + 1) * 4];
#pragma unroll
        for (int u = 0; u < 16; ++u) hh[u] = bf2f(h16[(size_t)ss[u] * HID + d]);
#pragma unroll
        for (int u = 0; u < 16; ++u) ee[u] = csr2[(size_t)2 * (j + u)];
#pragma unroll
        for (int u = 0; u < 16; ++u) {
          P0 = fmaf(ee[u].x, hh[u], P0);
          P1 = fmaf(ee[u].y, hh[u], P1);
          P2 = fmaf(ee[u].z, hh[u], P2);
          P3 = fmaf(ee[u].w, hh[u], P3);
        }
      }
      for (; j + 4 <= end; j += 4) {
        int ss[4];
        float hh[4];
        float4 ee[4];
#pragma unroll
        for (int u = 0; u < 4; ++u) ss[u] = csri[((size_t)2 * (j + u) + 1) * 4];
#pragma unroll
        for (int u = 0; u < 4; ++u) hh[u] = bf2f(h16[(size_t)ss[u] * HID + d]);
#pragma unroll
        for (int u = 0; u < 4; ++u) ee[u] = csr2[(size_t)2 * (j + u)];
#pragma unroll
        for (int u = 0; u < 4; ++u) {
          P0 = fmaf(ee[u].x, hh[u], P0);
          P1 = fmaf(ee[u].y, hh[u], P1);
          P2 = fmaf(ee[u].z, hh[u], P2);
          P3 = fmaf(ee[u].w, hh[u], P3);
        }
      }
      for (; j < end; ++j) {
        int s0 = csri[((size_t)2 * j + 1) * 4];
        float4 e0 = csr2[(size_t)2 * j];
        float h0 = bf2f(h16[(size_t)s0 * HID + d]);
        P0 = fmaf(e0.x, h0, P0);
        P1 = fmaf(e0.y, h0, P1);
        P2 = fmaf(e0.z, h0, P2);
        P3 = fmaf(e0.w, h0, P3);
      }
    }
    float acc = fmaf(P3, w3_, fmaf(P2, w2_, fmaf(P1, w1_, P0 * w0)));
    sagg[w * 4 + i][d] = acc;
  }
  __syncthreads();
  // ---- Phase B: MFMA node transform (m89 layouts, split-bf16) ----
  int l = tid & 63;
  int q = l & 15;
  int g = l >> 4;
  int node = base + q;
  if (node >= n) node = n - 1;   // clamp; stores guarded
  bf16x8 aghi[2], aglo[2], ahhi[2], ahlo[2];
#pragma unroll
  for (int kt = 0; kt < 2; ++kt) {
    int koff = kt * 32 + g * 8;
    const float* hp = h + (size_t)node * HID + koff;
    ahhi[kt] = *(const bf16x8*)(h16 + (size_t)node * HID + koff);
#pragma unroll
    for (int j = 0; j < 8; ++j) {
      float av = sagg[q][koff + j];
      unsigned short hi = f2bf(av);
      aghi[kt][j] = (short)hi;
      aglo[kt][j] = (short)f2bf(av - bf2f(hi));
      float r = hp[j] - bf2f((unsigned short)ahhi[kt][j]);
      ahlo[kt][j] = (short)f2bf(r);
    }
  }
  f32x4 aR = {0.f, 0.f, 0.f, 0.f};
  f32x4 aO = {0.f, 0.f, 0.f, 0.f};
  f32x4 aS = {0.f, 0.f, 0.f, 0.f};
#pragma unroll
  for (int kt = 0; kt < 2; ++kt) {
    int f = kt * 4 + w;
    const bf16x8* bRh = (const bf16x8*)(nwhi + (((size_t)0 * 8 + f) * 64 + l) * 8);
    const bf16x8* bRl = (const bf16x8*)(nwlo + (((size_t)0 * 8 + f) * 64 + l) * 8);
    const bf16x8* bOh = (const bf16x8*)(nwhi + (((size_t)1 * 8 + f) * 64 + l) * 8);
    const bf16x8* bOl = (const bf16x8*)(nwlo + (((size_t)1 * 8 + f) * 64 + l) * 8);
    const bf16x8* bSh = (const bf16x8*)(nwhi + (((size_t)2 * 8 + f) * 64 + l) * 8);
    const bf16x8* bSl = (const bf16x8*)(nwlo + (((size_t)2 * 8 + f) * 64 + l) * 8);
    aR = __builtin_amdgcn_mfma_f32_16x16x32_bf16(aglo[kt], *bRh, aR, 0, 0, 0);
    aR = __builtin_amdgcn_mfma_f32_16x16x32_bf16(aghi[kt], *bRl, aR, 0, 0, 0);
    aR = __builtin_amdgcn_mfma_f32_16x16x32_bf16(aghi[kt], *bRh, aR, 0, 0, 0);
    aO = __builtin_amdgcn_mfma_f32_16x16x32_bf16(ahlo[kt], *bOh, aO, 0, 0, 0);
    aO = __builtin_amdgcn_mfma_f32_16x16x32_bf16(ahhi[kt], *bOl, aO, 0, 0, 0);
    aO = __builtin_amdgcn_mfma_f32_16x16x32_bf16(ahhi[kt], *bOh, aO, 0, 0, 0);
    aS = __builtin_amdgcn_mfma_f32_16x16x32_bf16(ahlo[kt], *bSh, aS, 0, 0, 0);
    aS = __builtin_amdgcn_mfma_f32_16x16x32_bf16(ahhi[kt], *bSl, aS, 0, 0, 0);
    aS = __builtin_amdgcn_mfma_f32_16x16x32_bf16(ahhi[kt], *bSh, aS, 0, 0, 0);
  }
  int col = w * 16 + q;
  float bd = rel_b[col];
#pragma unroll
  for (int r = 0; r < 4; ++r) {
    int nd = base + g * 4 + r;
    if (nd < n) {
      float v = fmaxf(aR[r] + aO[r] + bd, 0.f) + aS[r];
      hn[(size_t)nd * HID + col] = v;
      hn16[(size_t)nd * HID + col] = f2bf(v);
    }
  }
}

// ---- MFMA head (r12-validated) ----
__global__ __launch_bounds__(256, 4)
void head_kernel(const float* __restrict__ h,
                 const unsigned short* __restrict__ h16,
                 const unsigned short* __restrict__ w1bhi,
                 const unsigned short* __restrict__ w1blo,
                 const float* __restrict__ b1,
                 const float* __restrict__ w2,
                 const float* __restrict__ b2,
                 float* __restrict__ out, int n) {
  __shared__ float red[4][16];
  int tid = threadIdx.x;
  int w = tid >> 6;
  int l = tid & 63;
  int row = l & 15;
  int g = l >> 4;
  int base = blockIdx.x * 16;
  int node = base + row;
  if (node >= n) node = n - 1;
  f32x4 acc[8];
#pragma unroll
  for (int t = 0; t < 8; ++t) acc[t] = (f32x4){0.f, 0.f, 0.f, 0.f};
#pragma unroll
  for (int kt = 0; kt < 2; ++kt) {
    int koff = kt * 32 + g * 8;
    bf16x8 ahi = *(const bf16x8*)(h16 + (size_t)node * HID + koff);
    const float* hp = h + (size_t)node * HID + koff;
    bf16x8 alo;
#pragma unroll
    for (int j = 0; j < 8; ++j) {
      float r = hp[j] - bf2f((unsigned short)ahi[j]);
      alo[j] = (short)f2bf(r);
    }
#pragma unroll
    for (int t = 0; t < 8; ++t) {
      int f = kt * 32 + w * 8 + t;
      bf16x8 bhi = *(const bf16x8*)(w1bhi + (size_t)f * 512 + l * 8);
      bf16x8 blo = *(const bf16x8*)(w1blo + (size_t)f * 512 + l * 8);
      acc[t] = __builtin_amdgcn_mfma_f32_16x16x32_bf16(alo, bhi, acc[t], 0, 0, 0);
      acc[t] = __builtin_amdgcn_mfma_f32_16x16x32_bf16(ahi, blo, acc[t], 0, 0, 0);
      acc[t] = __builtin_amdgcn_mfma_f32_16x16x32_bf16(ahi, bhi, acc[t], 0, 0, 0);
    }
  }
  float s0 = 0.f, s1 = 0.f, s2 = 0.f, s3 = 0.f;
#pragma unroll
  for (int t = 0; t < 8; ++t) {
    int ff = (w * 8 + t) * 16 + row;
    float bb = b1[ff];
    float ww = w2[ff];
    float xv, gl;
    xv = acc[t][0] + bb; gl = 0.5f * xv * (1.f + erff(xv * 0.70710678118654752f)); s0 = fmaf(gl, ww, s0);
    xv = acc[t][1] + bb; gl = 0.5f * xv * (1.f + erff(xv * 0.70710678118654752f)); s1 = fmaf(gl, ww, s1);
    xv = acc[t][2] + bb; gl = 0.5f * xv * (1.f + erff(xv * 0.70710678118654752f)); s2 = fmaf(gl, ww, s2);
    xv = acc[t][3] + bb; gl = 0.5f * xv * (1.f + erff(xv * 0.70710678118654752f)); s3 = fmaf(gl, ww, s3);
  }
#pragma unroll
  for (int off = 1; off < 16; off <<= 1) {
    s0 += __shfl_xor(s0, off);
    s1 += __shfl_xor(s1, off);
    s2 += __shfl_xor(s2, off);
    s3 += __shfl_xor(s3, off);
  }
  if ((l & 15) == 0) {
    red[w][g * 4 + 0] = s0;
    red[w][g * 4 + 1] = s1;
    red[w][g * 4 + 2] = s2;
    red[w][g * 4 + 3] = s3;
  }
  __syncthreads();
  if (tid < 16 && base + tid < n)
    out[base + tid] = red[0][tid] + red[1][tid] + red[2][tid] + red[3][tid] + b2[0];
}

extern "C" void kernel_launch(void* const* d_in, const int* in_sizes, int n_in,
                              void* d_out, int out_size, void* d_ws, size_t ws_size,
                              hipStream_t stream) {
  const int*   x          = (const int*)d_in[0];
  const int*   edge_index = (const int*)d_in[1];
  const float* edge_attr  = (const float*)d_in[2];
  const float* vert_emb   = (const float*)d_in[3];
  const float* edge_emb_w = (const float*)d_in[4];
  const float* edge_lin_w = (const float*)d_in[5];
  const float* rel_w      = (const float*)d_in[6];
  const float* rel_b      = (const float*)d_in[7];
  const float* root_w     = (const float*)d_in[8];
  const float* res_w      = (const float*)d_in[9];
  const float* w1         = (const float*)d_in[10];
  const float* b1         = (const float*)d_in[11];
  const float* w2         = (const float*)d_in[12];
  const float* b2         = (const float*)d_in[13];

  const int n = in_sizes[0];
  const int E = in_sizes[2] / 4;
  const int* src = edge_index;
  const int* dst = edge_index + E;
  const int nb = (n + 255) / 256;

  // workspace layout:
  //   Wl[2048] f | hA[n*64] f | hB[n*64] f | csr2[2E] float4 |
  //   row_ptr[n+1] | cursor[n] | deg[n] | bsum[256] | boff[256] (ints) |
  //   (16B-align) w1bhi[32768] | w1blo[32768] | nwhi[61440] | nwlo[61440] |
  //   h16A[n*64] | h16B[n*64] (u16)
  float* ws   = (float*)d_ws;
  float* Wl   = ws;
  float* hA   = ws + 2048;
  float* hB   = hA + (size_t)n * HID;
  float4* csr2 = (float4*)(hB + (size_t)n * HID);
  int* row_ptr = (int*)(csr2 + (size_t)2 * E);
  int* cursor  = row_ptr + (n + 1);
  int* deg     = cursor + n;
  int* bsum    = deg + n;
  int* boff    = bsum + 256;
  unsigned short* w1bhi = (unsigned short*)(((size_t)(boff + 256) + 15) & ~(size_t)15);
  unsigned short* w1blo = w1bhi + 64 * 512;
  unsigned short* nwhi  = w1blo + 64 * 512;
  unsigned short* nwlo  = nwhi + NLAY * 3 * 4096;
  unsigned short* h16A  = nwlo + NLAY * 3 * 4096;
  unsigned short* h16B  = h16A + (size_t)n * HID;

  prep_all_kernel<<<dim3(36), dim3(256), 0, stream>>>(
      edge_emb_w, edge_lin_w, w1, rel_w, root_w, res_w,
      Wl, w1bhi, w1blo, nwhi, nwlo);

  int totalHD = n * HID;
  embed_kernel<<<dim3((totalHD + 255) / 256), dim3(256), 0, stream>>>(
      x, vert_emb, hA, h16A, deg, n);

  hist_kernel<<<dim3((E + 255) / 256), dim3(256), 0, stream>>>(dst, deg, E);
  bsum_kernel<<<dim3(nb), dim3(256), 0, stream>>>(deg, bsum, n);
  bscan_kernel<<<dim3(1), dim3(256), 0, stream>>>(bsum, boff, nb);
  scan3_kernel<<<dim3(nb), dim3(256), 0, stream>>>(deg, boff, row_ptr, cursor, n);
  scatter_kernel<<<dim3((E + 255) / 256), dim3(256), 0, stream>>>(
      src, dst, (const float4*)edge_attr, cursor, csr2, E);

  float* hc = hA;
  float* hx = hB;
  unsigned short* h16c = h16A;
  unsigned short* h16x = h16B;
  for (int l = 0; l < NLAY; ++l) {
    layer_fused_kernel<<<dim3((n + 15) / 16), dim3(256), 0, stream>>>(
        row_ptr, csr2, Wl + l * 4 * HID, hc, h16c,
        nwhi + (size_t)l * 3 * 4096, nwlo + (size_t)l * 3 * 4096,
        rel_b + l * HID, hx, h16x, n);
    float* t = hc; hc = hx; hx = t;
    unsigned short* t16 = h16c; h16c = h16x; h16x = t16;
  }

  head_kernel<<<dim3((n + 15) / 16), dim3(256), 0, stream>>>(
      hc, h16c, w1bhi, w1blo, b1, w2, b2, (float*)d_out, n);
}